// Round 7
// baseline (348.597 us; speedup 1.0000x reference)
//
#include <hip/hip_runtime.h>
#include <math.h>

namespace {

constexpr int NH    = 16;
constexpr int DPROJ = 2320;
constexpr int NCH   = 8;

// ---- workspace layout (float offsets) ----
constexpr size_t F_STATS = 0;                  // 4
constexpr size_t F_PART  = 4;                  // 256
constexpr size_t F_T     = 260;                // (B*L,256) fp32
constexpr size_t SZ_T    = 2ull * 2048 * 256;  // 1048576
constexpr size_t F_YF    = F_T + SZ_T;
constexpr size_t F_YB    = F_YF + SZ_T;
constexpr size_t F_PR    = F_YB + SZ_T;
constexpr size_t F_SCR0  = F_PR + SZ_T;        // per-dir scratch base (x2)

// per-direction scratch (float offsets inside scr); bf16 tensors cast to ushort*
constexpr size_t S_ZX16  = 0;                  // (B*L,2320) bf16
constexpr size_t S_XP16  = 4751360;            // (B*L,1280) bf16
constexpr size_t S_DT    = S_XP16 + 2621440;   // (B*L,16) fp32
constexpr size_t S_ACS   = S_DT + 65536;
constexpr size_t S_TT    = S_ACS + 65536;
constexpr size_t S_ST    = S_TT + 256;         // chunk states fp32
constexpr size_t S_SIN   = S_ST + 2097152;     // Sin as bf16 now (ushort overlay)
constexpr size_t S_YHP16 = S_SIN + 2097152;    // (B*L,1024) bf16
constexpr size_t SZ_SCR  = S_YHP16 + 2097152;

constexpr size_t F_BF = F_SCR0 + 2 * SZ_SCR;   // ushort region base

typedef __bf16 bf16x8 __attribute__((ext_vector_type(8)));
typedef float  f32x4  __attribute__((ext_vector_type(4)));

__device__ __forceinline__ float silu(float v) { return v / (1.f + expf(-v)); }

__device__ __forceinline__ unsigned short f2bf(float f) {
  unsigned int u = __float_as_uint(f);
  return (unsigned short)((u + 0x7fffu + ((u >> 16) & 1u)) >> 16);
}
__device__ __forceinline__ float bf2f(unsigned short u) {
  return __uint_as_float((unsigned int)u << 16);
}

// ---------------- groupnorm stats ----------------
__global__ __launch_bounds__(256) void stats_partial_k(const float* __restrict__ x,
                                                       float* __restrict__ part) {
  int b = blockIdx.y, seg = blockIdx.x;
  const float4* base = (const float4*)(x + (size_t)b * 524288 + (size_t)seg * 8192);
  float s = 0.f, q = 0.f;
#pragma unroll
  for (int i = 0; i < 8; i++) {
    float4 v = base[threadIdx.x + i * 256];
    s += v.x + v.y + v.z + v.w;
    q += v.x * v.x + v.y * v.y + v.z * v.z + v.w * v.w;
  }
  for (int o = 32; o > 0; o >>= 1) { s += __shfl_down(s, o); q += __shfl_down(q, o); }
  __shared__ float ss[4], qq[4];
  int wid = threadIdx.x >> 6;
  if ((threadIdx.x & 63) == 0) { ss[wid] = s; qq[wid] = q; }
  __syncthreads();
  if (threadIdx.x == 0) {
    part[(b * 64 + seg) * 2]     = ss[0] + ss[1] + ss[2] + ss[3];
    part[(b * 64 + seg) * 2 + 1] = qq[0] + qq[1] + qq[2] + qq[3];
  }
}

__global__ __launch_bounds__(64) void stats_final_k(const float* __restrict__ part,
                                                    float* __restrict__ stats) {
  int b = blockIdx.x;
  float s = part[(b * 64 + threadIdx.x) * 2];
  float q = part[(b * 64 + threadIdx.x) * 2 + 1];
  for (int o = 32; o > 0; o >>= 1) { s += __shfl_down(s, o); q += __shfl_down(q, o); }
  if (threadIdx.x == 0) {
    float mu  = s / 524288.f;
    float var = q / 524288.f - mu * mu;
    stats[b * 2]     = mu;
    stats[b * 2 + 1] = rsqrtf(var + 1.1920929e-07f);
  }
}

// ---------------- normalize + transpose, LDS-tiled ----------------
__global__ __launch_bounds__(256) void normt2_k(const float* __restrict__ x,
                                                const float* __restrict__ gw,
                                                const float* __restrict__ gb,
                                                const float* __restrict__ stats,
                                                float* __restrict__ t,
                                                unsigned short* __restrict__ t16) {
  int l0 = blockIdx.x * 32, c0 = blockIdx.y * 32, b = blockIdx.z;
  int tx = threadIdx.x & 31, ty = threadIdx.x >> 5;
  float mu = stats[b * 2], rstd = stats[b * 2 + 1];
  __shared__ float tile[32][33];
#pragma unroll
  for (int i = 0; i < 4; i++) {
    int c = c0 + ty + i * 8;
    float v = x[(size_t)b * 524288 + (size_t)c * 2048 + l0 + tx];
    tile[ty + i * 8][tx] = (v - mu) * rstd * gw[c] + gb[c];
  }
  __syncthreads();
#pragma unroll
  for (int i = 0; i < 4; i++) {
    int ll = ty + i * 8;
    size_t o = (size_t)(b * 2048 + l0 + ll) * 256 + c0 + tx;
    float v = tile[tx][ll];
    t[o] = v;
    t16[o] = f2bf(v);
  }
}

// ---------------- all weight tensors -> bf16 ----------------
__global__ __launch_bounds__(256) void cvtw_k(
    const float* __restrict__ fiw, const float* __restrict__ biw,
    const float* __restrict__ fow, const float* __restrict__ bow,
    const float* __restrict__ pw,
    unsigned short* __restrict__ inw16, unsigned short* __restrict__ outw16,
    unsigned short* __restrict__ projw16) {
  int y = blockIdx.y;
  const float* src; unsigned short* dst; int n4;
  if (y == 0)      { src = fiw; dst = inw16;          n4 = 148480; }
  else if (y == 1) { src = biw; dst = inw16 + 593920; n4 = 148480; }
  else if (y == 2) { src = fow; dst = outw16;          n4 = 65536; }
  else if (y == 3) { src = bow; dst = outw16 + 262144; n4 = 65536; }
  else             { src = pw;  dst = projw16;         n4 = 32768; }
  int i = blockIdx.x * 256 + threadIdx.x;
  if (i < n4) {
    float4 v = ((const float4*)src)[i];
    ushort4 o;
    o.x = f2bf(v.x); o.y = f2bf(v.y); o.z = f2bf(v.z); o.w = f2bf(v.w);
    ((ushort4*)dst)[i] = o;
  }
}

// ---------------- bf16 MFMA GEMM: C = A(M,K)*B(N,K)^T; C fp32 or bf16 ----------------
__global__ __launch_bounds__(256) void gemm_bf16_k(
    const unsigned short* __restrict__ A, int lda, long sA,
    const unsigned short* __restrict__ B, int ldb, long sB,
    void* __restrict__ Cout, int ldc, long sC,
    int M, int N, int K, int flipsel, int obf) {
  int zb = blockIdx.z;
  A += (size_t)zb * sA;
  B += (size_t)zb * sB;
  int flip = flipsel ? (zb ? 2047 : 0) : 0;
  int m0 = blockIdx.y * 128, n0 = blockIdx.x * 128;
  __shared__ unsigned short As[128][40];
  __shared__ unsigned short Bs[128][40];
  int tid = threadIdx.x;
  int lane = tid & 63, wid = tid >> 6;
  int wr = (wid >> 1) * 64, wc = (wid & 1) * 64;
  int fr = lane & 15, fq = lane >> 4;
  int sr = tid >> 2;
  int sk = (tid & 3) * 8;
  f32x4 acc[4][4] = {};
  for (int k0 = 0; k0 < K; k0 += 32) {
#pragma unroll
    for (int i = 0; i < 2; i++) {
      int r = sr + i * 64;
      int gm = (m0 + r) ^ flip;
      *(bf16x8*)&As[r][sk] = *(const bf16x8*)&A[(size_t)gm * lda + k0 + sk];
      int gn = n0 + r;
      if (gn >= N) gn = N - 1;
      *(bf16x8*)&Bs[r][sk] = *(const bf16x8*)&B[(size_t)gn * ldb + k0 + sk];
    }
    __syncthreads();
    bf16x8 a[4], b[4];
#pragma unroll
    for (int m = 0; m < 4; m++) a[m] = *(const bf16x8*)&As[wr + m * 16 + fr][fq * 8];
#pragma unroll
    for (int n = 0; n < 4; n++) b[n] = *(const bf16x8*)&Bs[wc + n * 16 + fr][fq * 8];
#pragma unroll
    for (int m = 0; m < 4; m++)
#pragma unroll
      for (int n = 0; n < 4; n++)
        acc[m][n] = __builtin_amdgcn_mfma_f32_16x16x32_bf16(a[m], b[n], acc[m][n], 0, 0, 0);
    __syncthreads();
  }
  if (obf) {
    unsigned short* C16 = (unsigned short*)Cout + (size_t)zb * sC;
#pragma unroll
    for (int m = 0; m < 4; m++) {
      int row = m0 + wr + m * 16 + fq * 4;
#pragma unroll
      for (int n = 0; n < 4; n++) {
        int col = n0 + wc + n * 16 + fr;
        if (col < N) {
#pragma unroll
          for (int j = 0; j < 4; j++) C16[(size_t)(row + j) * ldc + col] = f2bf(acc[m][n][j]);
        }
      }
    }
  } else {
    float* C = (float*)Cout + (size_t)zb * sC;
#pragma unroll
    for (int m = 0; m < 4; m++) {
      int row = m0 + wr + m * 16 + fq * 4;
#pragma unroll
      for (int n = 0; n < 4; n++) {
        int col = n0 + wc + n * 16 + fr;
        if (col < N) {
#pragma unroll
          for (int j = 0; j < 4; j++) C[(size_t)(row + j) * ldc + col] = acc[m][n][j];
        }
      }
    }
  }
}

// ---------------- conv4 + silu, sliding-window, bf16 in/out ----------------
__global__ __launch_bounds__(256) void conv3_k(
    const float* __restrict__ fcw, const float* __restrict__ bcw,
    const float* __restrict__ fcb, const float* __restrict__ bcb,
    float* __restrict__ scr0, long DS) {
  int j = blockIdx.x * 256 + threadIdx.x;
  int l0 = blockIdx.y * 64;
  int b = blockIdx.z & 1, dir = blockIdx.z >> 1;
  float* scr = scr0 + (size_t)dir * DS;
  const unsigned short* zx16 = (const unsigned short*)(scr + S_ZX16);
  unsigned short* xp16 = (unsigned short*)(scr + S_XP16);
  const float* cwp = (dir ? bcw : fcw) + j * 4;
  float c0 = cwp[0], c1 = cwp[1], c2 = cwp[2], c3 = cwp[3];
  float cb = (dir ? bcb : fcb)[j];
  size_t colz = 1024 + j;
  float w0 = 0.f, w1 = 0.f, w2 = 0.f;
  if (l0 >= 3) {
    w0 = bf2f(zx16[(size_t)(b * 2048 + l0 - 3) * DPROJ + colz]);
    w1 = bf2f(zx16[(size_t)(b * 2048 + l0 - 2) * DPROJ + colz]);
    w2 = bf2f(zx16[(size_t)(b * 2048 + l0 - 1) * DPROJ + colz]);
  }
  for (int l = l0; l < l0 + 64; l++) {
    float cur = bf2f(zx16[(size_t)(b * 2048 + l) * DPROJ + colz]);
    float o = cb + c0 * w0 + c1 * w1 + c2 * w2 + c3 * cur;
    xp16[(size_t)(b * 2048 + l) * 1280 + j] = f2bf(silu(o));
    w0 = w1; w1 = w2; w2 = cur;
  }
}

// ---------------- fused dt + softplus + A + per-chunk scan ----------------
__global__ __launch_bounds__(256) void dscan_k(
    const float* __restrict__ t,
    const float* __restrict__ fiw, const float* __restrict__ biw,
    const float* __restrict__ fdtb, const float* __restrict__ bdtb,
    const float* __restrict__ fAlog, const float* __restrict__ bAlog,
    float* __restrict__ scr0, long DS) {
  int h = blockIdx.x, c = blockIdx.y;
  int b = blockIdx.z & 1, dir = blockIdx.z >> 1;
  const float* in_w = dir ? biw : fiw;
  float dtbv = (dir ? bdtb : fdtb)[h];
  float alog = (dir ? bAlog : fAlog)[h];
  float* scr = scr0 + (size_t)dir * DS;
  int l = threadIdx.x;
  int row = b * 2048 + c * 256 + l;
  int flip = dir ? 2047 : 0;
  __shared__ float sw[256];
  __shared__ float buf0[256], buf1[256];
  sw[l] = in_w[(size_t)(2304 + h) * 256 + l];
  __syncthreads();
  const float4* t4 = (const float4*)(t + (size_t)(row ^ flip) * 256);
  const float4* w4 = (const float4*)sw;
  float s = 0.f;
#pragma unroll 8
  for (int k = 0; k < 64; k++) {
    float4 a = t4[k], w = w4[k];
    s += a.x * w.x + a.y * w.y + a.z * w.z + a.w * w.w;
  }
  float rawv = s + dtbv;
  float d = (rawv > 20.f) ? rawv : log1pf(expf(rawv));
  (scr + S_DT)[(size_t)row * 16 + h] = d;
  buf0[l] = -expf(alog) * d;
  __syncthreads();
  float* src = buf0;
  float* dst = buf1;
  for (int off = 1; off < 256; off <<= 1) {
    float v = src[l];
    if (l >= off) v += src[l - off];
    dst[l] = v;
    __syncthreads();
    float* tmp = src; src = dst; dst = tmp;
  }
  float scn = src[l];
  int chidx = (b * NCH + c) * NH + h;
  (scr + S_ACS)[(size_t)chidx * 256 + l] = scn;
  if (l == 255) (scr + S_TT)[chidx] = scn;
}

// ---------------- materialize dtX^T (bf16) and B^T (bf16) ----------------
// dtxt16: [slot,h,p=64,s=2048]; bt16: [slot,n=128,s=2048]; slot = dir*2+b
__global__ __launch_bounds__(256) void dtxtbt_k(
    float* __restrict__ scr0, long DS,
    unsigned short* __restrict__ dtxt16, unsigned short* __restrict__ bt16) {
  int hh = blockIdx.y;                  // 0..17 (16,17 = B halves)
  int s0 = blockIdx.x * 128;
  int slot = blockIdx.z;
  int b = slot & 1, dir = slot >> 1;
  float* scr = scr0 + (size_t)dir * DS;
  const unsigned short* xp16 = (const unsigned short*)(scr + S_XP16);
  const float* dt = scr + S_DT;
  int tx = threadIdx.x & 31, ty = threadIdx.x >> 5;
  int colbase = (hh < 16) ? hh * 64 : 1024 + (hh - 16) * 64;
  __shared__ float tl[32][33];
  for (int ps = 0; ps < 2; ps++) {
    for (int ss = 0; ss < 4; ss++) {
      __syncthreads();
#pragma unroll
      for (int q = 0; q < 4; q++) {
        int sl = ty + q * 8;
        int row = b * 2048 + s0 + ss * 32 + sl;
        float v = bf2f(xp16[(size_t)row * 1280 + colbase + ps * 32 + tx]);
        if (hh < 16) v *= dt[(size_t)row * 16 + hh];
        tl[sl][tx] = v;
      }
      __syncthreads();
#pragma unroll
      for (int q = 0; q < 4; q++) {
        int pl = ty + q * 8;
        int p = ps * 32 + pl;
        int s = s0 + ss * 32 + tx;
        unsigned short o = f2bf(tl[tx][pl]);
        if (hh < 16)
          dtxt16[((size_t)(slot * 16 + hh) * 64 + p) * 2048 + s] = o;
        else
          bt16[((size_t)slot * 128 + (hh - 16) * 64 + p) * 2048 + s] = o;
      }
    }
  }
}

// ---------------- chunk states via MFMA: S[p=64][n-half=64] ----------------
__global__ __launch_bounds__(256) void states_mfma_k(
    float* __restrict__ scr0, long DS,
    const unsigned short* __restrict__ dtxt16, const unsigned short* __restrict__ bt16) {
  int h = blockIdx.x, c = blockIdx.y;
  int nh2 = blockIdx.z & 1, b = (blockIdx.z >> 1) & 1, dir = blockIdx.z >> 2;
  int slot = dir * 2 + b;
  float* scr = scr0 + (size_t)dir * DS;
  const float* Acs = scr + S_ACS;
  const float* Ttot = scr + S_TT;
  float* stout = scr + S_ST;
  int tid = threadIdx.x;
  int chidx = (b * NCH + c) * NH + h;
  size_t xtb = ((size_t)(slot * 16 + h) * 64) * 2048 + c * 256;
  size_t btb = ((size_t)slot * 128 + nh2 * 64) * 2048 + c * 256;
  __shared__ float sXs[256];
  __shared__ unsigned short At[64][40];
  __shared__ unsigned short Bt[64][40];
  {
    float a = Acs[(size_t)chidx * 256 + tid];
    float Tt = Ttot[chidx];
    sXs[tid] = __expf(Tt - a);
  }
  __syncthreads();
  int lane = tid & 63, w = tid >> 6;
  int fr = lane & 15, fq = lane >> 4;
  int sp = tid >> 2, sk = (tid & 3) * 8;
  f32x4 acc[4] = {};
  for (int k0 = 0; k0 < 256; k0 += 32) {
    {
      // At: dtXt rows (p), scaled by decay along k (s)
      ushort4 xa = *(const ushort4*)&dtxt16[xtb + (size_t)sp * 2048 + k0 + sk];
      ushort4 xb = *(const ushort4*)&dtxt16[xtb + (size_t)sp * 2048 + k0 + sk + 4];
      float4 w0 = *(const float4*)&sXs[k0 + sk];
      float4 w1 = *(const float4*)&sXs[k0 + sk + 4];
      unsigned short tmp[8];
      tmp[0] = f2bf(bf2f(xa.x) * w0.x); tmp[1] = f2bf(bf2f(xa.y) * w0.y);
      tmp[2] = f2bf(bf2f(xa.z) * w0.z); tmp[3] = f2bf(bf2f(xa.w) * w0.w);
      tmp[4] = f2bf(bf2f(xb.x) * w1.x); tmp[5] = f2bf(bf2f(xb.y) * w1.y);
      tmp[6] = f2bf(bf2f(xb.z) * w1.z); tmp[7] = f2bf(bf2f(xb.w) * w1.w);
      *(ushort4*)&At[sp][sk]     = *(ushort4*)&tmp[0];
      *(ushort4*)&At[sp][sk + 4] = *(ushort4*)&tmp[4];
      // Bt: pure copy of B^T rows
      *(bf16x8*)&Bt[sp][sk] = *(const bf16x8*)&bt16[btb + (size_t)sp * 2048 + k0 + sk];
    }
    __syncthreads();
    bf16x8 bb = *(const bf16x8*)&Bt[w * 16 + fr][fq * 8];
#pragma unroll
    for (int m = 0; m < 4; m++) {
      bf16x8 a = *(const bf16x8*)&At[m * 16 + fr][fq * 8];
      acc[m] = __builtin_amdgcn_mfma_f32_16x16x32_bf16(a, bb, acc[m], 0, 0, 0);
    }
    __syncthreads();
  }
#pragma unroll
  for (int m = 0; m < 4; m++) {
    int p = m * 16 + fq * 4;
    int nn = nh2 * 64 + w * 16 + fr;
#pragma unroll
    for (int j = 0; j < 4; j++)
      stout[(size_t)chidx * 8192 + (size_t)(p + j) * 128 + nn] = acc[m][j];
  }
}

// ---------------- inter-chunk recurrence (Sin -> bf16) ----------------
__global__ __launch_bounds__(256) void recur_k(float* __restrict__ scr0, long DS) {
  int h = blockIdx.x;
  int b = blockIdx.y & 1, dir = blockIdx.y >> 1;
  float* scr = scr0 + (size_t)dir * DS;
  const float* st = scr + S_ST;
  const float* Ttot = scr + S_TT;
  unsigned short* Sin16 = (unsigned short*)(scr + S_SIN);
  int e0 = threadIdx.x * 32;
  float4 s[8];
#pragma unroll
  for (int j = 0; j < 8; j++) s[j] = make_float4(0.f, 0.f, 0.f, 0.f);
  for (int c = 0; c < 8; c++) {
    int chidx = (b * NCH + c) * NH + h;
    size_t base = (size_t)chidx * 8192 + e0;
    const float4* si = (const float4*)(st + base);
    float dec = __expf(Ttot[chidx]);
#pragma unroll
    for (int j = 0; j < 8; j++) {
      ushort4 o;
      o.x = f2bf(s[j].x); o.y = f2bf(s[j].y); o.z = f2bf(s[j].z); o.w = f2bf(s[j].w);
      *(ushort4*)&Sin16[base + j * 4] = o;
      float4 v = si[j];
      s[j].x = s[j].x * dec + v.x; s[j].y = s[j].y * dec + v.y;
      s[j].z = s[j].z * dec + v.z; s[j].w = s[j].w * dec + v.w;
    }
  }
}

// ---------------- fused Y_diag + Y_off, flash-style, bf16 out ----------------
__global__ __launch_bounds__(256) void ydo2_k(
    float* __restrict__ scr0, long DS, const unsigned short* __restrict__ dtxt16) {
  int h = blockIdx.x;
  int cy = blockIdx.y;
  int c = cy >> 2, lt = cy & 3;
  int b = blockIdx.z & 1, dir = blockIdx.z >> 1;
  int slot = dir * 2 + b;
  float* scr = scr0 + (size_t)dir * DS;
  const float* Acs = scr + S_ACS;
  const unsigned short* xp16 = (const unsigned short*)(scr + S_XP16);
  const unsigned short* Sin16 = (const unsigned short*)(scr + S_SIN);
  unsigned short* yhp16 = (unsigned short*)(scr + S_YHP16);
  int tid = threadIdx.x;
  int lane = tid & 63, w = tid >> 6;
  int fr = lane & 15, fq = lane >> 4;
  int row0 = b * 2048 + c * 256;
  int chidx = (b * NCH + c) * NH + h;
  int l0 = lt * 64;
  size_t xtb = ((size_t)(slot * 16 + h) * 64) * 2048 + c * 256;

  __shared__ unsigned short sBS[64][136];  // Sin^T (p x n128), then B tiles (s x n128)
  __shared__ unsigned short sXt[64][72];   // dtX^T (p x s64)
  __shared__ unsigned short sP[64][72];    // masked decay*CB (l x s64)
  __shared__ float sA[64], sAs[64];

  // C fragments: direct global loads (read-once)
  bf16x8 af[4];
#pragma unroll
  for (int k = 0; k < 4; k++)
    af[k] = *(const bf16x8*)&xp16[(size_t)(row0 + l0 + w * 16 + fr) * 1280 + 1152 + k * 32 + fq * 8];

  // stage Sin^T (bf16 rows)
#pragma unroll
  for (int i = 0; i < 4; i++) {
    int chunk = tid + i * 256;
    int p = chunk >> 4, n8 = (chunk & 15) * 8;
    *(bf16x8*)&sBS[p][n8] = *(const bf16x8*)&Sin16[(size_t)chidx * 8192 + p * 128 + n8];
  }
  if (tid < 64) sA[tid] = Acs[(size_t)chidx * 256 + l0 + tid];
  __syncthreads();

  // Y_off: acc = C @ Sin^T, scaled by exp(A_l)
  f32x4 acc[4] = {};
#pragma unroll
  for (int n = 0; n < 4; n++) {
#pragma unroll
    for (int k = 0; k < 4; k++) {
      bf16x8 bb = *(const bf16x8*)&sBS[n * 16 + fr][k * 32 + fq * 8];
      acc[n] = __builtin_amdgcn_mfma_f32_16x16x32_bf16(af[k], bb, acc[n], 0, 0, 0);
    }
  }
  {
    int lrow = w * 16 + fq * 4;
    float el[4];
#pragma unroll
    for (int j = 0; j < 4; j++) el[j] = __expf(sA[lrow + j]);
#pragma unroll
    for (int n = 0; n < 4; n++)
#pragma unroll
      for (int j = 0; j < 4; j++) acc[n][j] *= el[j];
  }

  for (int st = 0; st <= lt; st++) {
    __syncthreads();
    int srow0 = row0 + st * 64;
    // B tile (s x n128) — natural layout copy
#pragma unroll
    for (int i = 0; i < 4; i++) {
      int chunk = tid + i * 256;
      int r = chunk >> 4, c8 = (chunk & 15) * 8;
      *(bf16x8*)&sBS[r][c8] = *(const bf16x8*)&xp16[(size_t)(srow0 + r) * 1280 + 1024 + c8];
    }
    // dtX^T tile (p x s64) — pre-transposed copy
#pragma unroll
    for (int i = 0; i < 2; i++) {
      int chunk = tid + i * 256;
      int p = chunk >> 3, s8 = (chunk & 7) * 8;
      *(bf16x8*)&sXt[p][s8] = *(const bf16x8*)&dtxt16[xtb + (size_t)p * 2048 + st * 64 + s8];
    }
    if (tid < 64) sAs[tid] = Acs[(size_t)chidx * 256 + st * 64 + tid];
    __syncthreads();

    // CB = C @ B^T
    f32x4 cb[4] = {};
#pragma unroll
    for (int n = 0; n < 4; n++) {
#pragma unroll
      for (int k = 0; k < 4; k++) {
        bf16x8 bb = *(const bf16x8*)&sBS[n * 16 + fr][k * 32 + fq * 8];
        cb[n] = __builtin_amdgcn_mfma_f32_16x16x32_bf16(af[k], bb, cb[n], 0, 0, 0);
      }
    }
    // decay + mask -> P (bf16, wave-private rows)
    {
      int lrow = w * 16 + fq * 4;
      float al[4];
#pragma unroll
      for (int j = 0; j < 4; j++) al[j] = sA[lrow + j];
      bool full = (st < lt);
#pragma unroll
      for (int n = 0; n < 4; n++) {
        int srow = n * 16 + fr;
        float as_ = sAs[srow];
#pragma unroll
        for (int j = 0; j < 4; j++) {
          float v = (full || srow <= lrow + j) ? cb[n][j] * __expf(al[j] - as_) : 0.f;
          sP[lrow + j][srow] = f2bf(v);
        }
      }
    }
    // PV: acc += P @ dtX
#pragma unroll
    for (int k2 = 0; k2 < 2; k2++) {
      bf16x8 pa = *(const bf16x8*)&sP[w * 16 + fr][k2 * 32 + fq * 8];
#pragma unroll
      for (int n = 0; n < 4; n++) {
        bf16x8 bb = *(const bf16x8*)&sXt[n * 16 + fr][k2 * 32 + fq * 8];
        acc[n] = __builtin_amdgcn_mfma_f32_16x16x32_bf16(pa, bb, acc[n], 0, 0, 0);
      }
    }
  }

#pragma unroll
  for (int n = 0; n < 4; n++) {
    int p = n * 16 + fr;
#pragma unroll
    for (int j = 0; j < 4; j++) {
      int row = row0 + l0 + w * 16 + fq * 4 + j;
      yhp16[(size_t)row * 1024 + h * 64 + p] = f2bf(acc[n][j]);
    }
  }
}

// ---------------- gate + x*D + RMS norm, all bf16, in place ----------------
__global__ __launch_bounds__(256) void gate_rms_k(
    float* __restrict__ scr0, long DS,
    const float* __restrict__ fD, const float* __restrict__ bD,
    const float* __restrict__ fnw, const float* __restrict__ bnw) {
  int row = blockIdx.x;
  int dir = blockIdx.y;
  float* scr = scr0 + (size_t)dir * DS;
  unsigned short* yhp16 = (unsigned short*)(scr + S_YHP16);
  const unsigned short* xp16 = (const unsigned short*)(scr + S_XP16);
  const unsigned short* zx16 = (const unsigned short*)(scr + S_ZX16);
  const float* Dv = dir ? bD : fD;
  const float* nw = dir ? bnw : fnw;
  float g[4];
  float ss = 0.f;
#pragma unroll
  for (int k = 0; k < 4; k++) {
    int i = threadIdx.x + k * 256;
    int h = i >> 6;
    float y = bf2f(yhp16[(size_t)row * 1024 + i]) +
              bf2f(xp16[(size_t)row * 1280 + i]) * Dv[h];
    float z = bf2f(zx16[(size_t)row * DPROJ + i]);
    float gg = y * silu(z);
    ss += gg * gg;
    g[k] = gg;
  }
  for (int o = 32; o > 0; o >>= 1) ss += __shfl_down(ss, o);
  __shared__ float red[5];
  int wid = threadIdx.x >> 6;
  if ((threadIdx.x & 63) == 0) red[wid] = ss;
  __syncthreads();
  if (threadIdx.x == 0) red[4] = red[0] + red[1] + red[2] + red[3];
  __syncthreads();
  float rstd = rsqrtf(red[4] / 1024.f + 1e-5f);
#pragma unroll
  for (int k = 0; k < 4; k++) {
    int i = threadIdx.x + k * 256;
    yhp16[(size_t)row * 1024 + i] = f2bf(g[k] * rstd * nw[i]);
  }
}

// ---------------- final proj GEMM with fused r-build ----------------
__global__ __launch_bounds__(256) void gemm_r_k(
    const float* __restrict__ yf, const float* __restrict__ yb,
    const float* __restrict__ t, const unsigned short* __restrict__ Bw,
    float* __restrict__ C) {
  int m0 = blockIdx.y * 128, n0 = blockIdx.x * 128;
  __shared__ unsigned short As[128][40];
  __shared__ unsigned short Bs[128][40];
  int tid = threadIdx.x;
  int lane = tid & 63, wid = tid >> 6;
  int wr = (wid >> 1) * 64, wc = (wid & 1) * 64;
  int fr = lane & 15, fq = lane >> 4;
  int sr = tid >> 2;
  int sk = (tid & 3) * 8;
  f32x4 acc[4][4] = {};
  for (int k0 = 0; k0 < 512; k0 += 32) {
#pragma unroll
    for (int i = 0; i < 2; i++) {
      int r = sr + i * 64;
      int gm = m0 + r;
      const float* ybase;
      int cc;
      if (k0 < 256) { ybase = yf + (size_t)gm * 256; cc = k0 + sk; }
      else          { ybase = yb + (size_t)(gm ^ 2047) * 256; cc = k0 - 256 + sk; }
      const float* tbase = t + (size_t)gm * 256 + cc;
      unsigned short tmp[8];
#pragma unroll
      for (int q = 0; q < 8; q += 4) {
        float4 a = *(const float4*)(ybase + cc + q);
        float4 b = *(const float4*)(tbase + q);
        tmp[q + 0] = f2bf(a.x + b.x); tmp[q + 1] = f2bf(a.y + b.y);
        tmp[q + 2] = f2bf(a.z + b.z); tmp[q + 3] = f2bf(a.w + b.w);
      }
      *(ushort4*)&As[r][sk]     = *(ushort4*)&tmp[0];
      *(ushort4*)&As[r][sk + 4] = *(ushort4*)&tmp[4];
      int gn = n0 + r;
      if (gn >= 256) gn = 255;
      *(bf16x8*)&Bs[r][sk] = *(const bf16x8*)&Bw[(size_t)gn * 512 + k0 + sk];
    }
    __syncthreads();
    bf16x8 a[4], b[4];
#pragma unroll
    for (int m = 0; m < 4; m++) a[m] = *(const bf16x8*)&As[wr + m * 16 + fr][fq * 8];
#pragma unroll
    for (int n = 0; n < 4; n++) b[n] = *(const bf16x8*)&Bs[wc + n * 16 + fr][fq * 8];
#pragma unroll
    for (int m = 0; m < 4; m++)
#pragma unroll
      for (int n = 0; n < 4; n++)
        acc[m][n] = __builtin_amdgcn_mfma_f32_16x16x32_bf16(a[m], b[n], acc[m][n], 0, 0, 0);
    __syncthreads();
  }
#pragma unroll
  for (int m = 0; m < 4; m++) {
    int row = m0 + wr + m * 16 + fq * 4;
#pragma unroll
    for (int n = 0; n < 4; n++) {
      int col = n0 + wc + n * 16 + fr;
      if (col < 256) {
#pragma unroll
        for (int j = 0; j < 4; j++) C[(size_t)(row + j) * 256 + col] = acc[m][n][j];
      }
    }
  }
}

// ---------------- out = x + pr^T + proj_b, LDS-tiled transpose ----------------
__global__ __launch_bounds__(256) void final_add2_k(const float* __restrict__ x,
                                                    const float* __restrict__ pr,
                                                    const float* __restrict__ pb,
                                                    float* __restrict__ out) {
  int l0 = blockIdx.x * 32, c0 = blockIdx.y * 32, b = blockIdx.z;
  int tx = threadIdx.x & 31, ty = threadIdx.x >> 5;
  __shared__ float tile[32][33];
#pragma unroll
  for (int i = 0; i < 4; i++) {
    int ll = ty + i * 8;
    tile[ll][tx] = pr[(size_t)(b * 2048 + l0 + ll) * 256 + c0 + tx];
  }
  __syncthreads();
#pragma unroll
  for (int i = 0; i < 4; i++) {
    int ch = c0 + ty + i * 8;
    size_t o = (size_t)b * 524288 + (size_t)ch * 2048 + l0 + tx;
    out[o] = x[o] + tile[tx][ty + i * 8] + pb[ch];
  }
}

}  // namespace

extern "C" void kernel_launch(void* const* d_in, const int* in_sizes, int n_in,
                              void* d_out, int out_size, void* d_ws, size_t ws_size,
                              hipStream_t stream) {
  (void)in_sizes; (void)n_in; (void)out_size; (void)ws_size;
  const float* x      = (const float*)d_in[0];
  const float* gn_w   = (const float*)d_in[1];
  const float* gn_b   = (const float*)d_in[2];
  const float* proj_w = (const float*)d_in[3];
  const float* proj_b = (const float*)d_in[4];
  const float* fiw  = (const float*)d_in[5];
  const float* fcw  = (const float*)d_in[6];
  const float* fcb  = (const float*)d_in[7];
  const float* fdtb = (const float*)d_in[8];
  const float* fAl  = (const float*)d_in[9];
  const float* fD   = (const float*)d_in[10];
  const float* fnw  = (const float*)d_in[11];
  const float* fow  = (const float*)d_in[12];
  const float* biw  = (const float*)d_in[13];
  const float* bcw  = (const float*)d_in[14];
  const float* bcb  = (const float*)d_in[15];
  const float* bdtb = (const float*)d_in[16];
  const float* bAl  = (const float*)d_in[17];
  const float* bD   = (const float*)d_in[18];
  const float* bnw  = (const float*)d_in[19];
  const float* bow  = (const float*)d_in[20];
  float* out = (float*)d_out;
  float* ws  = (float*)d_ws;
  float* scr0 = ws + F_SCR0;
  const long DS = (long)SZ_SCR;
  const long DSU = DS * 2;

  unsigned short* t16     = (unsigned short*)(ws + F_BF);
  unsigned short* inw16   = t16 + 1048576;
  unsigned short* outw16  = inw16 + 1187840;
  unsigned short* projw16 = outw16 + 524288;
  unsigned short* dtxt16  = projw16 + 131072;
  unsigned short* bt16    = dtxt16 + 8388608;
  unsigned short* zx16    = (unsigned short*)(scr0 + S_ZX16);
  unsigned short* yhp16   = (unsigned short*)(scr0 + S_YHP16);
  float* pr = ws + F_PR;

  // groupnorm + transpose
  stats_partial_k<<<dim3(64, 2), 256, 0, stream>>>(x, ws + F_PART);
  stats_final_k<<<2, 64, 0, stream>>>(ws + F_PART, ws + F_STATS);
  normt2_k<<<dim3(64, 8, 2), 256, 0, stream>>>(x, gn_w, gn_b, ws + F_STATS, ws + F_T, t16);
  // weights -> bf16
  cvtw_k<<<dim3(580, 5), 256, 0, stream>>>(fiw, biw, fow, bow, proj_w, inw16, outw16, projw16);

  // in_proj (bf16 out), both dirs batched
  gemm_bf16_k<<<dim3(19, 32, 2), 256, 0, stream>>>(
      t16, 256, 0, inw16, 256, 593920L, zx16, DPROJ, DSU, 4096, DPROJ, 256, 1, 1);
  // conv + silu (sliding window, bf16)
  conv3_k<<<dim3(5, 32, 4), 256, 0, stream>>>(fcw, bcw, fcb, bcb, scr0, DS);
  // dt + scan (fp32)
  dscan_k<<<dim3(NH, NCH, 4), 256, 0, stream>>>(
      ws + F_T, fiw, biw, fdtb, bdtb, fAl, bAl, scr0, DS);
  // materialize dtX^T and B^T
  dtxtbt_k<<<dim3(16, 18, 4), 256, 0, stream>>>(scr0, DS, dtxt16, bt16);
  // chunk states
  states_mfma_k<<<dim3(NH, NCH, 8), 256, 0, stream>>>(scr0, DS, dtxt16, bt16);
  // inter-chunk recurrence (Sin -> bf16)
  recur_k<<<dim3(NH, 4), 256, 0, stream>>>(scr0, DS);
  // fused Y_diag + Y_off
  ydo2_k<<<dim3(NH, NCH * 4, 4), 256, 0, stream>>>(scr0, DS, dtxt16);
  // gate + RMS norm (in place on yhp16)
  gate_rms_k<<<dim3(4096, 2), 256, 0, stream>>>(scr0, DS, fD, bD, fnw, bnw);
  // out_proj (fp32 out), both dirs batched
  gemm_bf16_k<<<dim3(2, 32, 2), 256, 0, stream>>>(
      yhp16, 1024, DSU, outw16, 1024, 262144L, ws + F_YF, 256, (long)SZ_T,
      4096, 256, 1024, 0, 0);
  // final proj with fused r-build
  gemm_r_k<<<dim3(2, 32, 1), 256, 0, stream>>>(ws + F_YF, ws + F_YB, ws + F_T, projw16, pr);
  // out = x + pr^T + proj_b
  final_add2_k<<<dim3(64, 8, 2), 256, 0, stream>>>(x, pr, proj_b, out);
}

// Round 8
// 328.945 us; speedup vs baseline: 1.0597x; 1.0597x over previous
//
#include <hip/hip_runtime.h>
#include <math.h>

namespace {

constexpr int NH    = 16;
constexpr int DPROJ = 2320;
constexpr int NCH   = 8;

// ---- workspace layout (float offsets) ----
constexpr size_t F_STATS = 0;                  // 4
constexpr size_t F_PART  = 4;                  // 256
constexpr size_t F_T     = 260;                // (B*L,256) fp32
constexpr size_t SZ_T    = 2ull * 2048 * 256;  // 1048576
constexpr size_t F_YF    = F_T + SZ_T;         // yf16 (ushort overlay)
constexpr size_t F_YB    = F_YF + SZ_T;        // yb16 (ushort overlay)
constexpr size_t F_PR    = F_YB + SZ_T;
constexpr size_t F_SCR0  = F_PR + SZ_T;        // per-dir scratch base (x2)

// per-direction scratch (float offsets inside scr); bf16 tensors cast to ushort*
constexpr size_t S_ZX16  = 0;                  // (B*L,2320) bf16
constexpr size_t S_XP16  = 4751360;            // (B*L,1280) bf16
constexpr size_t S_DT    = S_XP16 + 2621440;   // (B*L,16) fp32
constexpr size_t S_ACS   = S_DT + 65536;
constexpr size_t S_TT    = S_ACS + 65536;
constexpr size_t S_ST    = S_TT + 256;         // chunk states fp32
constexpr size_t S_SIN   = S_ST + 2097152;     // Sin bf16 (ushort overlay)
constexpr size_t S_YHP16 = S_SIN + 2097152;    // (B*L,1024) bf16
constexpr size_t SZ_SCR  = S_YHP16 + 2097152;

constexpr size_t F_BF = F_SCR0 + 2 * SZ_SCR;   // ushort region base

typedef __bf16 bf16x8 __attribute__((ext_vector_type(8)));
typedef float  f32x4  __attribute__((ext_vector_type(4)));

__device__ __forceinline__ float silu(float v) { return v / (1.f + expf(-v)); }

__device__ __forceinline__ unsigned short f2bf(float f) {
  unsigned int u = __float_as_uint(f);
  return (unsigned short)((u + 0x7fffu + ((u >> 16) & 1u)) >> 16);
}
__device__ __forceinline__ float bf2f(unsigned short u) {
  return __uint_as_float((unsigned int)u << 16);
}

// async global->LDS, 16B per lane (dest = wave-uniform base + lane*16)
__device__ __forceinline__ void gl_lds16(const unsigned short* g, unsigned short* l) {
  typedef __attribute__((address_space(1))) const unsigned int gq;
  typedef __attribute__((address_space(3))) unsigned int lq;
  __builtin_amdgcn_global_load_lds((gq*)g, (lq*)l, 16, 0, 0);
}

// ---------------- groupnorm stats ----------------
__global__ __launch_bounds__(256) void stats_partial_k(const float* __restrict__ x,
                                                       float* __restrict__ part) {
  int b = blockIdx.y, seg = blockIdx.x;
  const float4* base = (const float4*)(x + (size_t)b * 524288 + (size_t)seg * 8192);
  float s = 0.f, q = 0.f;
#pragma unroll
  for (int i = 0; i < 8; i++) {
    float4 v = base[threadIdx.x + i * 256];
    s += v.x + v.y + v.z + v.w;
    q += v.x * v.x + v.y * v.y + v.z * v.z + v.w * v.w;
  }
  for (int o = 32; o > 0; o >>= 1) { s += __shfl_down(s, o); q += __shfl_down(q, o); }
  __shared__ float ss[4], qq[4];
  int wid = threadIdx.x >> 6;
  if ((threadIdx.x & 63) == 0) { ss[wid] = s; qq[wid] = q; }
  __syncthreads();
  if (threadIdx.x == 0) {
    part[(b * 64 + seg) * 2]     = ss[0] + ss[1] + ss[2] + ss[3];
    part[(b * 64 + seg) * 2 + 1] = qq[0] + qq[1] + qq[2] + qq[3];
  }
}

__global__ __launch_bounds__(64) void stats_final_k(const float* __restrict__ part,
                                                    float* __restrict__ stats) {
  int b = blockIdx.x;
  float s = part[(b * 64 + threadIdx.x) * 2];
  float q = part[(b * 64 + threadIdx.x) * 2 + 1];
  for (int o = 32; o > 0; o >>= 1) { s += __shfl_down(s, o); q += __shfl_down(q, o); }
  if (threadIdx.x == 0) {
    float mu  = s / 524288.f;
    float var = q / 524288.f - mu * mu;
    stats[b * 2]     = mu;
    stats[b * 2 + 1] = rsqrtf(var + 1.1920929e-07f);
  }
}

// ---------------- normalize + transpose, LDS-tiled ----------------
__global__ __launch_bounds__(256) void normt2_k(const float* __restrict__ x,
                                                const float* __restrict__ gw,
                                                const float* __restrict__ gb,
                                                const float* __restrict__ stats,
                                                float* __restrict__ t,
                                                unsigned short* __restrict__ t16) {
  int l0 = blockIdx.x * 32, c0 = blockIdx.y * 32, b = blockIdx.z;
  int tx = threadIdx.x & 31, ty = threadIdx.x >> 5;
  float mu = stats[b * 2], rstd = stats[b * 2 + 1];
  __shared__ float tile[32][33];
#pragma unroll
  for (int i = 0; i < 4; i++) {
    int c = c0 + ty + i * 8;
    float v = x[(size_t)b * 524288 + (size_t)c * 2048 + l0 + tx];
    tile[ty + i * 8][tx] = (v - mu) * rstd * gw[c] + gb[c];
  }
  __syncthreads();
#pragma unroll
  for (int i = 0; i < 4; i++) {
    int ll = ty + i * 8;
    size_t o = (size_t)(b * 2048 + l0 + ll) * 256 + c0 + tx;
    float v = tile[tx][ll];
    t[o] = v;
    t16[o] = f2bf(v);
  }
}

// ---------------- all weight tensors -> bf16 ----------------
__global__ __launch_bounds__(256) void cvtw_k(
    const float* __restrict__ fiw, const float* __restrict__ biw,
    const float* __restrict__ fow, const float* __restrict__ bow,
    const float* __restrict__ pw,
    unsigned short* __restrict__ inw16, unsigned short* __restrict__ outw16,
    unsigned short* __restrict__ projw16) {
  int y = blockIdx.y;
  const float* src; unsigned short* dst; int n4;
  if (y == 0)      { src = fiw; dst = inw16;          n4 = 148480; }
  else if (y == 1) { src = biw; dst = inw16 + 593920; n4 = 148480; }
  else if (y == 2) { src = fow; dst = outw16;          n4 = 65536; }
  else if (y == 3) { src = bow; dst = outw16 + 262144; n4 = 65536; }
  else             { src = pw;  dst = projw16;         n4 = 32768; }
  int i = blockIdx.x * 256 + threadIdx.x;
  if (i < n4) {
    float4 v = ((const float4*)src)[i];
    ushort4 o;
    o.x = f2bf(v.x); o.y = f2bf(v.y); o.z = f2bf(v.z); o.w = f2bf(v.w);
    ((ushort4*)dst)[i] = o;
  }
}

// ---------------- bf16 MFMA GEMM with global_load_lds staging (m97 recipe) ----------------
// C = A(M,K)*B(N,K)^T; linear LDS [128][32]; flip XORs A row; C fp32 or bf16
__global__ __launch_bounds__(256) void gemm2_k(
    const unsigned short* __restrict__ A, int lda, long sA,
    const unsigned short* __restrict__ B, int ldb, long sB,
    void* __restrict__ Cout, int ldc, long sC,
    int M, int N, int K, int flipsel, int obf) {
  int zb = blockIdx.z;
  A += (size_t)zb * sA;
  B += (size_t)zb * sB;
  int flip = flipsel ? (zb ? 2047 : 0) : 0;
  int m0 = blockIdx.y * 128, n0 = blockIdx.x * 128;
  __shared__ unsigned short As[4096];   // [128][32] linear
  __shared__ unsigned short Bs[4096];
  int tid = threadIdx.x;
  int lane = tid & 63, wid = tid >> 6;
  int wr = (wid >> 1) * 64, wc = (wid & 1) * 64;
  int fr = lane & 15, fq = lane >> 4;
  f32x4 acc[4][4] = {};
  for (int k0 = 0; k0 < K; k0 += 32) {
#pragma unroll
    for (int i = 0; i < 2; i++) {
      int idx = tid + i * 256;           // 16B-chunk id, 0..511
      int r = idx >> 2, c8 = (idx & 3) * 8;
      int ldsoff = (i * 256 + wid * 64) * 8;  // wave-uniform base (ushorts)
      gl_lds16(&A[(size_t)((m0 + r) ^ flip) * lda + k0 + c8], As + ldsoff);
      gl_lds16(&B[(size_t)(n0 + r) * ldb + k0 + c8], Bs + ldsoff);
    }
    __syncthreads();
    bf16x8 a[4], b[4];
#pragma unroll
    for (int m = 0; m < 4; m++) a[m] = *(const bf16x8*)&As[(wr + m * 16 + fr) * 32 + fq * 8];
#pragma unroll
    for (int n = 0; n < 4; n++) b[n] = *(const bf16x8*)&Bs[(wc + n * 16 + fr) * 32 + fq * 8];
#pragma unroll
    for (int m = 0; m < 4; m++)
#pragma unroll
      for (int n = 0; n < 4; n++)
        acc[m][n] = __builtin_amdgcn_mfma_f32_16x16x32_bf16(a[m], b[n], acc[m][n], 0, 0, 0);
    __syncthreads();
  }
  if (obf) {
    unsigned short* C16 = (unsigned short*)Cout + (size_t)zb * sC;
#pragma unroll
    for (int m = 0; m < 4; m++) {
      int row = m0 + wr + m * 16 + fq * 4;
#pragma unroll
      for (int n = 0; n < 4; n++) {
        int col = n0 + wc + n * 16 + fr;
        if (col < N) {
#pragma unroll
          for (int j = 0; j < 4; j++) C16[(size_t)(row + j) * ldc + col] = f2bf(acc[m][n][j]);
        }
      }
    }
  } else {
    float* C = (float*)Cout + (size_t)zb * sC;
#pragma unroll
    for (int m = 0; m < 4; m++) {
      int row = m0 + wr + m * 16 + fq * 4;
#pragma unroll
      for (int n = 0; n < 4; n++) {
        int col = n0 + wc + n * 16 + fr;
        if (col < N) {
#pragma unroll
          for (int j = 0; j < 4; j++) C[(size_t)(row + j) * ldc + col] = acc[m][n][j];
        }
      }
    }
  }
}

// ---------------- conv4 + silu + fused transpose outputs ----------------
// writes xp16 row-major AND dtX^T (dt-baked) / B^T rows straight from registers
__global__ __launch_bounds__(256) void convt_k(
    const float* __restrict__ fcw, const float* __restrict__ bcw,
    const float* __restrict__ fcb, const float* __restrict__ bcb,
    float* __restrict__ scr0, long DS,
    unsigned short* __restrict__ dtxt16, unsigned short* __restrict__ bt16) {
  int bx = blockIdx.x;                      // 0..4
  int j = bx * 256 + threadIdx.x;           // channel 0..1279
  int l0 = blockIdx.y * 64;
  int b = blockIdx.z & 1, dir = blockIdx.z >> 1, slot = blockIdx.z;
  float* scr = scr0 + (size_t)dir * DS;
  const unsigned short* zx16 = (const unsigned short*)(scr + S_ZX16);
  unsigned short* xp16 = (unsigned short*)(scr + S_XP16);
  const float* dtp = scr + S_DT;
  const float* cwp = (dir ? bcw : fcw) + j * 4;
  float c0 = cwp[0], c1 = cwp[1], c2 = cwp[2], c3 = cwp[3];
  float cb = (dir ? bcb : fcb)[j];
  size_t colz = 1024 + j;
  bool isX = (bx < 4);
  int h = j >> 6;                            // head (valid for isX)
  float w0 = 0.f, w1 = 0.f, w2 = 0.f;
  if (l0 >= 3) {
    w0 = bf2f(zx16[(size_t)(b * 2048 + l0 - 3) * DPROJ + colz]);
    w1 = bf2f(zx16[(size_t)(b * 2048 + l0 - 2) * DPROJ + colz]);
    w2 = bf2f(zx16[(size_t)(b * 2048 + l0 - 1) * DPROJ + colz]);
  }
  bf16x8 rb[8];
#pragma unroll
  for (int li = 0; li < 64; li++) {
    int row = b * 2048 + l0 + li;
    float cur = bf2f(zx16[(size_t)row * DPROJ + colz]);
    float o = silu(cb + c0 * w0 + c1 * w1 + c2 * w2 + c3 * cur);
    xp16[(size_t)row * 1280 + j] = f2bf(o);
    float mult = isX ? dtp[(size_t)row * 16 + h] : 1.f;
    rb[li >> 3][li & 7] = (__bf16)(o * mult);
    w0 = w1; w1 = w2; w2 = cur;
  }
  // transposed row write (128B per thread)
  unsigned short* base = nullptr;
  if (isX) {
    base = dtxt16 + ((size_t)(slot * 16 + h) * 64 + (j & 63)) * 2048 + l0;
  } else if (threadIdx.x < 128) {            // B channels (1024..1151)
    base = bt16 + ((size_t)slot * 128 + threadIdx.x) * 2048 + l0;
  }
  if (base) {
#pragma unroll
    for (int i = 0; i < 8; i++) *(bf16x8*)(base + i * 8) = rb[i];
  }
}

// ---------------- fused dt + softplus + A + per-chunk scan ----------------
__global__ __launch_bounds__(256) void dscan_k(
    const float* __restrict__ t,
    const float* __restrict__ fiw, const float* __restrict__ biw,
    const float* __restrict__ fdtb, const float* __restrict__ bdtb,
    const float* __restrict__ fAlog, const float* __restrict__ bAlog,
    float* __restrict__ scr0, long DS) {
  int h = blockIdx.x, c = blockIdx.y;
  int b = blockIdx.z & 1, dir = blockIdx.z >> 1;
  const float* in_w = dir ? biw : fiw;
  float dtbv = (dir ? bdtb : fdtb)[h];
  float alog = (dir ? bAlog : fAlog)[h];
  float* scr = scr0 + (size_t)dir * DS;
  int l = threadIdx.x;
  int row = b * 2048 + c * 256 + l;
  int flip = dir ? 2047 : 0;
  __shared__ float sw[256];
  __shared__ float buf0[256], buf1[256];
  sw[l] = in_w[(size_t)(2304 + h) * 256 + l];
  __syncthreads();
  const float4* t4 = (const float4*)(t + (size_t)(row ^ flip) * 256);
  const float4* w4 = (const float4*)sw;
  float s = 0.f;
#pragma unroll 8
  for (int k = 0; k < 64; k++) {
    float4 a = t4[k], w = w4[k];
    s += a.x * w.x + a.y * w.y + a.z * w.z + a.w * w.w;
  }
  float rawv = s + dtbv;
  float d = (rawv > 20.f) ? rawv : log1pf(expf(rawv));
  (scr + S_DT)[(size_t)row * 16 + h] = d;
  buf0[l] = -expf(alog) * d;
  __syncthreads();
  float* src = buf0;
  float* dst = buf1;
  for (int off = 1; off < 256; off <<= 1) {
    float v = src[l];
    if (l >= off) v += src[l - off];
    dst[l] = v;
    __syncthreads();
    float* tmp = src; src = dst; dst = tmp;
  }
  float scn = src[l];
  int chidx = (b * NCH + c) * NH + h;
  (scr + S_ACS)[(size_t)chidx * 256 + l] = scn;
  if (l == 255) (scr + S_TT)[chidx] = scn;
}

// ---------------- chunk states via MFMA: S[p=64][n-half=64] ----------------
__global__ __launch_bounds__(256) void states_mfma_k(
    float* __restrict__ scr0, long DS,
    const unsigned short* __restrict__ dtxt16, const unsigned short* __restrict__ bt16) {
  int h = blockIdx.x, c = blockIdx.y;
  int nh2 = blockIdx.z & 1, b = (blockIdx.z >> 1) & 1, dir = blockIdx.z >> 2;
  int slot = dir * 2 + b;
  float* scr = scr0 + (size_t)dir * DS;
  const float* Acs = scr + S_ACS;
  const float* Ttot = scr + S_TT;
  float* stout = scr + S_ST;
  int tid = threadIdx.x;
  int chidx = (b * NCH + c) * NH + h;
  size_t xtb = ((size_t)(slot * 16 + h) * 64) * 2048 + c * 256;
  size_t btb = ((size_t)slot * 128 + nh2 * 64) * 2048 + c * 256;
  __shared__ float sXs[256];
  __shared__ unsigned short At[64][40];
  __shared__ unsigned short Bt[64][40];
  {
    float a = Acs[(size_t)chidx * 256 + tid];
    float Tt = Ttot[chidx];
    sXs[tid] = __expf(Tt - a);
  }
  __syncthreads();
  int lane = tid & 63, w = tid >> 6;
  int fr = lane & 15, fq = lane >> 4;
  int sp = tid >> 2, sk = (tid & 3) * 8;
  f32x4 acc[4] = {};
  for (int k0 = 0; k0 < 256; k0 += 32) {
    {
      ushort4 xa = *(const ushort4*)&dtxt16[xtb + (size_t)sp * 2048 + k0 + sk];
      ushort4 xb = *(const ushort4*)&dtxt16[xtb + (size_t)sp * 2048 + k0 + sk + 4];
      float4 w0 = *(const float4*)&sXs[k0 + sk];
      float4 w1 = *(const float4*)&sXs[k0 + sk + 4];
      unsigned short tmp[8];
      tmp[0] = f2bf(bf2f(xa.x) * w0.x); tmp[1] = f2bf(bf2f(xa.y) * w0.y);
      tmp[2] = f2bf(bf2f(xa.z) * w0.z); tmp[3] = f2bf(bf2f(xa.w) * w0.w);
      tmp[4] = f2bf(bf2f(xb.x) * w1.x); tmp[5] = f2bf(bf2f(xb.y) * w1.y);
      tmp[6] = f2bf(bf2f(xb.z) * w1.z); tmp[7] = f2bf(bf2f(xb.w) * w1.w);
      *(ushort4*)&At[sp][sk]     = *(ushort4*)&tmp[0];
      *(ushort4*)&At[sp][sk + 4] = *(ushort4*)&tmp[4];
      *(bf16x8*)&Bt[sp][sk] = *(const bf16x8*)&bt16[btb + (size_t)sp * 2048 + k0 + sk];
    }
    __syncthreads();
    bf16x8 bb = *(const bf16x8*)&Bt[w * 16 + fr][fq * 8];
#pragma unroll
    for (int m = 0; m < 4; m++) {
      bf16x8 a = *(const bf16x8*)&At[m * 16 + fr][fq * 8];
      acc[m] = __builtin_amdgcn_mfma_f32_16x16x32_bf16(a, bb, acc[m], 0, 0, 0);
    }
    __syncthreads();
  }
#pragma unroll
  for (int m = 0; m < 4; m++) {
    int p = m * 16 + fq * 4;
    int nn = nh2 * 64 + w * 16 + fr;
#pragma unroll
    for (int j = 0; j < 4; j++)
      stout[(size_t)chidx * 8192 + (size_t)(p + j) * 128 + nn] = acc[m][j];
  }
}

// ---------------- inter-chunk recurrence (Sin -> bf16) ----------------
__global__ __launch_bounds__(256) void recur_k(float* __restrict__ scr0, long DS) {
  int h = blockIdx.x;
  int b = blockIdx.y & 1, dir = blockIdx.y >> 1;
  float* scr = scr0 + (size_t)dir * DS;
  const float* st = scr + S_ST;
  const float* Ttot = scr + S_TT;
  unsigned short* Sin16 = (unsigned short*)(scr + S_SIN);
  int e0 = threadIdx.x * 32;
  float4 s[8];
#pragma unroll
  for (int j = 0; j < 8; j++) s[j] = make_float4(0.f, 0.f, 0.f, 0.f);
  for (int c = 0; c < 8; c++) {
    int chidx = (b * NCH + c) * NH + h;
    size_t base = (size_t)chidx * 8192 + e0;
    const float4* si = (const float4*)(st + base);
    float dec = __expf(Ttot[chidx]);
#pragma unroll
    for (int j = 0; j < 8; j++) {
      ushort4 o;
      o.x = f2bf(s[j].x); o.y = f2bf(s[j].y); o.z = f2bf(s[j].z); o.w = f2bf(s[j].w);
      *(ushort4*)&Sin16[base + j * 4] = o;
      float4 v = si[j];
      s[j].x = s[j].x * dec + v.x; s[j].y = s[j].y * dec + v.y;
      s[j].z = s[j].z * dec + v.z; s[j].w = s[j].w * dec + v.w;
    }
  }
}

// ---------------- fused Y_diag + Y_off, flash-style, bf16 out ----------------
__global__ __launch_bounds__(256) void ydo2_k(
    float* __restrict__ scr0, long DS, const unsigned short* __restrict__ dtxt16) {
  int h = blockIdx.x;
  int cy = blockIdx.y;
  int c = cy >> 2, lt = cy & 3;
  int b = blockIdx.z & 1, dir = blockIdx.z >> 1;
  int slot = dir * 2 + b;
  float* scr = scr0 + (size_t)dir * DS;
  const float* Acs = scr + S_ACS;
  const unsigned short* xp16 = (const unsigned short*)(scr + S_XP16);
  const unsigned short* Sin16 = (const unsigned short*)(scr + S_SIN);
  unsigned short* yhp16 = (unsigned short*)(scr + S_YHP16);
  int tid = threadIdx.x;
  int lane = tid & 63, w = tid >> 6;
  int fr = lane & 15, fq = lane >> 4;
  int row0 = b * 2048 + c * 256;
  int chidx = (b * NCH + c) * NH + h;
  int l0 = lt * 64;
  size_t xtb = ((size_t)(slot * 16 + h) * 64) * 2048 + c * 256;

  __shared__ unsigned short sBS[64][136];
  __shared__ unsigned short sXt[64][72];
  __shared__ unsigned short sP[64][72];
  __shared__ float sA[64], sAs[64];

  bf16x8 af[4];
#pragma unroll
  for (int k = 0; k < 4; k++)
    af[k] = *(const bf16x8*)&xp16[(size_t)(row0 + l0 + w * 16 + fr) * 1280 + 1152 + k * 32 + fq * 8];

#pragma unroll
  for (int i = 0; i < 4; i++) {
    int chunk = tid + i * 256;
    int p = chunk >> 4, n8 = (chunk & 15) * 8;
    *(bf16x8*)&sBS[p][n8] = *(const bf16x8*)&Sin16[(size_t)chidx * 8192 + p * 128 + n8];
  }
  if (tid < 64) sA[tid] = Acs[(size_t)chidx * 256 + l0 + tid];
  __syncthreads();

  f32x4 acc[4] = {};
#pragma unroll
  for (int n = 0; n < 4; n++) {
#pragma unroll
    for (int k = 0; k < 4; k++) {
      bf16x8 bb = *(const bf16x8*)&sBS[n * 16 + fr][k * 32 + fq * 8];
      acc[n] = __builtin_amdgcn_mfma_f32_16x16x32_bf16(af[k], bb, acc[n], 0, 0, 0);
    }
  }
  {
    int lrow = w * 16 + fq * 4;
    float el[4];
#pragma unroll
    for (int j = 0; j < 4; j++) el[j] = __expf(sA[lrow + j]);
#pragma unroll
    for (int n = 0; n < 4; n++)
#pragma unroll
      for (int j = 0; j < 4; j++) acc[n][j] *= el[j];
  }

  for (int st = 0; st <= lt; st++) {
    __syncthreads();
    int srow0 = row0 + st * 64;
#pragma unroll
    for (int i = 0; i < 4; i++) {
      int chunk = tid + i * 256;
      int r = chunk >> 4, c8 = (chunk & 15) * 8;
      *(bf16x8*)&sBS[r][c8] = *(const bf16x8*)&xp16[(size_t)(srow0 + r) * 1280 + 1024 + c8];
    }
#pragma unroll
    for (int i = 0; i < 2; i++) {
      int chunk = tid + i * 256;
      int p = chunk >> 3, s8 = (chunk & 7) * 8;
      *(bf16x8*)&sXt[p][s8] = *(const bf16x8*)&dtxt16[xtb + (size_t)p * 2048 + st * 64 + s8];
    }
    if (tid < 64) sAs[tid] = Acs[(size_t)chidx * 256 + st * 64 + tid];
    __syncthreads();

    f32x4 cb[4] = {};
#pragma unroll
    for (int n = 0; n < 4; n++) {
#pragma unroll
      for (int k = 0; k < 4; k++) {
        bf16x8 bb = *(const bf16x8*)&sBS[n * 16 + fr][k * 32 + fq * 8];
        cb[n] = __builtin_amdgcn_mfma_f32_16x16x32_bf16(af[k], bb, cb[n], 0, 0, 0);
      }
    }
    {
      int lrow = w * 16 + fq * 4;
      float al[4];
#pragma unroll
      for (int j = 0; j < 4; j++) al[j] = sA[lrow + j];
      bool full = (st < lt);
#pragma unroll
      for (int n = 0; n < 4; n++) {
        int srow = n * 16 + fr;
        float as_ = sAs[srow];
#pragma unroll
        for (int j = 0; j < 4; j++) {
          float v = (full || srow <= lrow + j) ? cb[n][j] * __expf(al[j] - as_) : 0.f;
          sP[lrow + j][srow] = f2bf(v);
        }
      }
    }
#pragma unroll
    for (int k2 = 0; k2 < 2; k2++) {
      bf16x8 pa = *(const bf16x8*)&sP[w * 16 + fr][k2 * 32 + fq * 8];
#pragma unroll
      for (int n = 0; n < 4; n++) {
        bf16x8 bb = *(const bf16x8*)&sXt[n * 16 + fr][k2 * 32 + fq * 8];
        acc[n] = __builtin_amdgcn_mfma_f32_16x16x32_bf16(pa, bb, acc[n], 0, 0, 0);
      }
    }
  }

#pragma unroll
  for (int n = 0; n < 4; n++) {
    int p = n * 16 + fr;
#pragma unroll
    for (int j = 0; j < 4; j++) {
      int row = row0 + l0 + w * 16 + fq * 4 + j;
      yhp16[(size_t)row * 1024 + h * 64 + p] = f2bf(acc[n][j]);
    }
  }
}

// ---------------- gate + x*D + RMS norm, all bf16, in place ----------------
__global__ __launch_bounds__(256) void gate_rms_k(
    float* __restrict__ scr0, long DS,
    const float* __restrict__ fD, const float* __restrict__ bD,
    const float* __restrict__ fnw, const float* __restrict__ bnw) {
  int row = blockIdx.x;
  int dir = blockIdx.y;
  float* scr = scr0 + (size_t)dir * DS;
  unsigned short* yhp16 = (unsigned short*)(scr + S_YHP16);
  const unsigned short* xp16 = (const unsigned short*)(scr + S_XP16);
  const unsigned short* zx16 = (const unsigned short*)(scr + S_ZX16);
  const float* Dv = dir ? bD : fD;
  const float* nw = dir ? bnw : fnw;
  float g[4];
  float ss = 0.f;
#pragma unroll
  for (int k = 0; k < 4; k++) {
    int i = threadIdx.x + k * 256;
    int h = i >> 6;
    float y = bf2f(yhp16[(size_t)row * 1024 + i]) +
              bf2f(xp16[(size_t)row * 1280 + i]) * Dv[h];
    float z = bf2f(zx16[(size_t)row * DPROJ + i]);
    float gg = y * silu(z);
    ss += gg * gg;
    g[k] = gg;
  }
  for (int o = 32; o > 0; o >>= 1) ss += __shfl_down(ss, o);
  __shared__ float red[5];
  int wid = threadIdx.x >> 6;
  if ((threadIdx.x & 63) == 0) red[wid] = ss;
  __syncthreads();
  if (threadIdx.x == 0) red[4] = red[0] + red[1] + red[2] + red[3];
  __syncthreads();
  float rstd = rsqrtf(red[4] / 1024.f + 1e-5f);
#pragma unroll
  for (int k = 0; k < 4; k++) {
    int i = threadIdx.x + k * 256;
    yhp16[(size_t)row * 1024 + i] = f2bf(g[k] * rstd * nw[i]);
  }
}

// ---------------- final proj GEMM with fused r-build (bf16 y inputs) ----------------
__global__ __launch_bounds__(256) void gemm_r_k(
    const unsigned short* __restrict__ yf16, const unsigned short* __restrict__ yb16,
    const unsigned short* __restrict__ t16, const unsigned short* __restrict__ Bw,
    float* __restrict__ C) {
  int m0 = blockIdx.y * 128, n0 = blockIdx.x * 128;
  __shared__ unsigned short As[128][40];
  __shared__ unsigned short Bs[4096];   // linear for gl_lds
  int tid = threadIdx.x;
  int lane = tid & 63, wid = tid >> 6;
  int wr = (wid >> 1) * 64, wc = (wid & 1) * 64;
  int fr = lane & 15, fq = lane >> 4;
  int sr = tid >> 2;
  int sk = (tid & 3) * 8;
  f32x4 acc[4][4] = {};
  for (int k0 = 0; k0 < 512; k0 += 32) {
#pragma unroll
    for (int i = 0; i < 2; i++) {
      int idx = tid + i * 256;
      int r = idx >> 2, c8 = (idx & 3) * 8;
      int ldsoff = (i * 256 + wid * 64) * 8;
      gl_lds16(&Bw[(size_t)(n0 + r) * 512 + k0 + c8], Bs + ldsoff);
      // A: build r = y + t on the fly
      int rr = sr + i * 64;
      int gm = m0 + rr;
      const unsigned short* ybase;
      int cc;
      if (k0 < 256) { ybase = yf16 + (size_t)gm * 256; cc = k0 + sk; }
      else          { ybase = yb16 + (size_t)(gm ^ 2047) * 256; cc = k0 - 256 + sk; }
      const unsigned short* tbase = t16 + (size_t)gm * 256 + cc;
      unsigned short tmp[8];
#pragma unroll
      for (int q = 0; q < 8; q += 4) {
        ushort4 a = *(const ushort4*)(ybase + cc + q);
        ushort4 tv = *(const ushort4*)(tbase + q);
        tmp[q + 0] = f2bf(bf2f(a.x) + bf2f(tv.x));
        tmp[q + 1] = f2bf(bf2f(a.y) + bf2f(tv.y));
        tmp[q + 2] = f2bf(bf2f(a.z) + bf2f(tv.z));
        tmp[q + 3] = f2bf(bf2f(a.w) + bf2f(tv.w));
      }
      *(ushort4*)&As[rr][sk]     = *(ushort4*)&tmp[0];
      *(ushort4*)&As[rr][sk + 4] = *(ushort4*)&tmp[4];
    }
    __syncthreads();
    bf16x8 a[4], b[4];
#pragma unroll
    for (int m = 0; m < 4; m++) a[m] = *(const bf16x8*)&As[wr + m * 16 + fr][fq * 8];
#pragma unroll
    for (int n = 0; n < 4; n++) b[n] = *(const bf16x8*)&Bs[(wc + n * 16 + fr) * 32 + fq * 8];
#pragma unroll
    for (int m = 0; m < 4; m++)
#pragma unroll
      for (int n = 0; n < 4; n++)
        acc[m][n] = __builtin_amdgcn_mfma_f32_16x16x32_bf16(a[m], b[n], acc[m][n], 0, 0, 0);
    __syncthreads();
  }
#pragma unroll
  for (int m = 0; m < 4; m++) {
    int row = m0 + wr + m * 16 + fq * 4;
#pragma unroll
    for (int n = 0; n < 4; n++) {
      int col = n0 + wc + n * 16 + fr;
      if (col < 256) {
#pragma unroll
        for (int j = 0; j < 4; j++) C[(size_t)(row + j) * 256 + col] = acc[m][n][j];
      }
    }
  }
}

// ---------------- out = x + pr^T + proj_b, LDS-tiled transpose ----------------
__global__ __launch_bounds__(256) void final_add2_k(const float* __restrict__ x,
                                                    const float* __restrict__ pr,
                                                    const float* __restrict__ pb,
                                                    float* __restrict__ out) {
  int l0 = blockIdx.x * 32, c0 = blockIdx.y * 32, b = blockIdx.z;
  int tx = threadIdx.x & 31, ty = threadIdx.x >> 5;
  __shared__ float tile[32][33];
#pragma unroll
  for (int i = 0; i < 4; i++) {
    int ll = ty + i * 8;
    tile[ll][tx] = pr[(size_t)(b * 2048 + l0 + ll) * 256 + c0 + tx];
  }
  __syncthreads();
#pragma unroll
  for (int i = 0; i < 4; i++) {
    int ch = c0 + ty + i * 8;
    size_t o = (size_t)b * 524288 + (size_t)ch * 2048 + l0 + tx;
    out[o] = x[o] + tile[tx][ty + i * 8] + pb[ch];
  }
}

}  // namespace

extern "C" void kernel_launch(void* const* d_in, const int* in_sizes, int n_in,
                              void* d_out, int out_size, void* d_ws, size_t ws_size,
                              hipStream_t stream) {
  (void)in_sizes; (void)n_in; (void)out_size; (void)ws_size;
  const float* x      = (const float*)d_in[0];
  const float* gn_w   = (const float*)d_in[1];
  const float* gn_b   = (const float*)d_in[2];
  const float* proj_w = (const float*)d_in[3];
  const float* proj_b = (const float*)d_in[4];
  const float* fiw  = (const float*)d_in[5];
  const float* fcw  = (const float*)d_in[6];
  const float* fcb  = (const float*)d_in[7];
  const float* fdtb = (const float*)d_in[8];
  const float* fAl  = (const float*)d_in[9];
  const float* fD   = (const float*)d_in[10];
  const float* fnw  = (const float*)d_in[11];
  const float* fow  = (const float*)d_in[12];
  const float* biw  = (const float*)d_in[13];
  const float* bcw  = (const float*)d_in[14];
  const float* bcb  = (const float*)d_in[15];
  const float* bdtb = (const float*)d_in[16];
  const float* bAl  = (const float*)d_in[17];
  const float* bD   = (const float*)d_in[18];
  const float* bnw  = (const float*)d_in[19];
  const float* bow  = (const float*)d_in[20];
  float* out = (float*)d_out;
  float* ws  = (float*)d_ws;
  float* scr0 = ws + F_SCR0;
  const long DS = (long)SZ_SCR;
  const long DSU = DS * 2;

  unsigned short* t16     = (unsigned short*)(ws + F_BF);
  unsigned short* inw16   = t16 + 1048576;
  unsigned short* outw16  = inw16 + 1187840;
  unsigned short* projw16 = outw16 + 524288;
  unsigned short* dtxt16  = projw16 + 131072;
  unsigned short* bt16    = dtxt16 + 8388608;
  unsigned short* zx16    = (unsigned short*)(scr0 + S_ZX16);
  unsigned short* yhp16   = (unsigned short*)(scr0 + S_YHP16);
  unsigned short* yf16    = (unsigned short*)(ws + F_YF);
  unsigned short* yb16    = (unsigned short*)(ws + F_YB);
  float* pr = ws + F_PR;

  // groupnorm + transpose
  stats_partial_k<<<dim3(64, 2), 256, 0, stream>>>(x, ws + F_PART);
  stats_final_k<<<2, 64, 0, stream>>>(ws + F_PART, ws + F_STATS);
  normt2_k<<<dim3(64, 8, 2), 256, 0, stream>>>(x, gn_w, gn_b, ws + F_STATS, ws + F_T, t16);
  // weights -> bf16
  cvtw_k<<<dim3(580, 5), 256, 0, stream>>>(fiw, biw, fow, bow, proj_w, inw16, outw16, projw16);

  // in_proj (bf16 out), both dirs batched, async-LDS staging
  gemm2_k<<<dim3(19, 32, 2), 256, 0, stream>>>(
      t16, 256, 0, inw16, 256, 593920L, zx16, DPROJ, DSU, 4096, DPROJ, 256, 1, 1);
  // dt + scan (fp32) — before conv (needs t only)
  dscan_k<<<dim3(NH, NCH, 4), 256, 0, stream>>>(
      ws + F_T, fiw, biw, fdtb, bdtb, fAl, bAl, scr0, DS);
  // conv + silu + fused dtX^T / B^T transpose from registers
  convt_k<<<dim3(5, 32, 4), 256, 0, stream>>>(fcw, bcw, fcb, bcb, scr0, DS, dtxt16, bt16);
  // chunk states
  states_mfma_k<<<dim3(NH, NCH, 8), 256, 0, stream>>>(scr0, DS, dtxt16, bt16);
  // inter-chunk recurrence (Sin -> bf16)
  recur_k<<<dim3(NH, 4), 256, 0, stream>>>(scr0, DS);
  // fused Y_diag + Y_off
  ydo2_k<<<dim3(NH, NCH * 4, 4), 256, 0, stream>>>(scr0, DS, dtxt16);
  // gate + RMS norm (in place on yhp16)
  gate_rms_k<<<dim3(4096, 2), 256, 0, stream>>>(scr0, DS, fD, bD, fnw, bnw);
  // out_proj -> yf16 / yb16 (bf16), both dirs batched
  gemm2_k<<<dim3(2, 32, 2), 256, 0, stream>>>(
      yhp16, 1024, DSU, outw16, 1024, 262144L, yf16, 256, 2097152L,
      4096, 256, 1024, 0, 1);
  // final proj with fused r-build (bf16 inputs)
  gemm_r_k<<<dim3(2, 32, 1), 256, 0, stream>>>(yf16, yb16, t16, projw16, pr);
  // out = x + pr^T + proj_b
  final_add2_k<<<dim3(64, 8, 2), 256, 0, stream>>>(x, pr, proj_b, out);
}

// Round 10
// 323.161 us; speedup vs baseline: 1.0787x; 1.0179x over previous
//
#include <hip/hip_runtime.h>
#include <math.h>

namespace {

constexpr int NH    = 16;
constexpr int DPROJ = 2320;
constexpr int NCH   = 8;

// ---- workspace layout (float offsets) ----
constexpr size_t F_STATS = 0;                  // 4
constexpr size_t F_PART  = 4;                  // 256
constexpr size_t F_T     = 260;                // (B*L,256) fp32
constexpr size_t SZ_T    = 2ull * 2048 * 256;  // 1048576
constexpr size_t F_PRP   = F_T + SZ_T;         // 3 split-K partials, each SZ_T fp32
constexpr size_t F_SCR0  = F_PRP + 3 * SZ_T;   // per-dir scratch base (x2)

// per-direction scratch (float offsets inside scr); bf16 tensors cast to ushort*
constexpr size_t S_ZX16  = 0;                  // (B*L,2320) bf16
constexpr size_t S_XP16  = 4751360;            // (B*L,1280) bf16
constexpr size_t S_DT    = S_XP16 + 2621440;   // (B*L,16) fp32
constexpr size_t S_ACS   = S_DT + 65536;
constexpr size_t S_TT    = S_ACS + 65536;
constexpr size_t S_ST    = S_TT + 256;         // chunk states fp32
constexpr size_t S_SIN   = S_ST + 2097152;     // Sin bf16 (ushort overlay)
constexpr size_t S_YHP16 = S_SIN + 2097152;    // (B*L,1024) bf16
constexpr size_t SZ_SCR  = S_YHP16 + 2097152;

constexpr size_t F_BF = F_SCR0 + 2 * SZ_SCR;   // ushort region base

typedef __bf16 bf16x8 __attribute__((ext_vector_type(8)));
typedef float  f32x4  __attribute__((ext_vector_type(4)));

__device__ __forceinline__ float silu(float v) { return v / (1.f + expf(-v)); }

__device__ __forceinline__ unsigned short f2bf(float f) {
  unsigned int u = __float_as_uint(f);
  return (unsigned short)((u + 0x7fffu + ((u >> 16) & 1u)) >> 16);
}
__device__ __forceinline__ float bf2f(unsigned short u) {
  return __uint_as_float((unsigned int)u << 16);
}

// async global->LDS, 16B per lane (dest = wave-uniform base + lane*16)
__device__ __forceinline__ void gl_lds16(const unsigned short* g, unsigned short* l) {
  typedef __attribute__((address_space(1))) const unsigned int gq;
  typedef __attribute__((address_space(3))) unsigned int lq;
  __builtin_amdgcn_global_load_lds((gq*)g, (lq*)l, 16, 0, 0);
}

// ---------------- groupnorm stats ----------------
__global__ __launch_bounds__(256) void stats_partial_k(const float* __restrict__ x,
                                                       float* __restrict__ part) {
  int b = blockIdx.y, seg = blockIdx.x;
  const float4* base = (const float4*)(x + (size_t)b * 524288 + (size_t)seg * 8192);
  float s = 0.f, q = 0.f;
#pragma unroll
  for (int i = 0; i < 8; i++) {
    float4 v = base[threadIdx.x + i * 256];
    s += v.x + v.y + v.z + v.w;
    q += v.x * v.x + v.y * v.y + v.z * v.z + v.w * v.w;
  }
  for (int o = 32; o > 0; o >>= 1) { s += __shfl_down(s, o); q += __shfl_down(q, o); }
  __shared__ float ss[4], qq[4];
  int wid = threadIdx.x >> 6;
  if ((threadIdx.x & 63) == 0) { ss[wid] = s; qq[wid] = q; }
  __syncthreads();
  if (threadIdx.x == 0) {
    part[(b * 64 + seg) * 2]     = ss[0] + ss[1] + ss[2] + ss[3];
    part[(b * 64 + seg) * 2 + 1] = qq[0] + qq[1] + qq[2] + qq[3];
  }
}

__global__ __launch_bounds__(64) void stats_final_k(const float* __restrict__ part,
                                                    float* __restrict__ stats) {
  int b = blockIdx.x;
  float s = part[(b * 64 + threadIdx.x) * 2];
  float q = part[(b * 64 + threadIdx.x) * 2 + 1];
  for (int o = 32; o > 0; o >>= 1) { s += __shfl_down(s, o); q += __shfl_down(q, o); }
  if (threadIdx.x == 0) {
    float mu  = s / 524288.f;
    float var = q / 524288.f - mu * mu;
    stats[b * 2]     = mu;
    stats[b * 2 + 1] = rsqrtf(var + 1.1920929e-07f);
  }
}

// ---------------- normalize + transpose, LDS-tiled ----------------
__global__ __launch_bounds__(256) void normt2_k(const float* __restrict__ x,
                                                const float* __restrict__ gw,
                                                const float* __restrict__ gb,
                                                const float* __restrict__ stats,
                                                float* __restrict__ t,
                                                unsigned short* __restrict__ t16) {
  int l0 = blockIdx.x * 32, c0 = blockIdx.y * 32, b = blockIdx.z;
  int tx = threadIdx.x & 31, ty = threadIdx.x >> 5;
  float mu = stats[b * 2], rstd = stats[b * 2 + 1];
  __shared__ float tile[32][33];
#pragma unroll
  for (int i = 0; i < 4; i++) {
    int c = c0 + ty + i * 8;
    float v = x[(size_t)b * 524288 + (size_t)c * 2048 + l0 + tx];
    tile[ty + i * 8][tx] = (v - mu) * rstd * gw[c] + gb[c];
  }
  __syncthreads();
#pragma unroll
  for (int i = 0; i < 4; i++) {
    int ll = ty + i * 8;
    size_t o = (size_t)(b * 2048 + l0 + ll) * 256 + c0 + tx;
    float v = tile[tx][ll];
    t[o] = v;
    t16[o] = f2bf(v);
  }
}

// ---------------- in_proj weights -> bf16; tw = P1+P2 -> bf16 ----------------
__global__ __launch_bounds__(256) void cvtw_k(
    const float* __restrict__ fiw, const float* __restrict__ biw,
    const float* __restrict__ pw,
    unsigned short* __restrict__ inw16, unsigned short* __restrict__ W16) {
  int y = blockIdx.y;
  int i = blockIdx.x * 256 + threadIdx.x;
  if (y == 2) {
    if (i < 16384) {
      int o = i >> 6, c4 = i & 63;
      float4 a = ((const float4*)pw)[(size_t)o * 128 + c4];
      float4 b = ((const float4*)pw)[(size_t)o * 128 + 64 + c4];
      ushort4 r;
      r.x = f2bf(a.x + b.x); r.y = f2bf(a.y + b.y);
      r.z = f2bf(a.z + b.z); r.w = f2bf(a.w + b.w);
      ((ushort4*)(W16 + 524288))[i] = r;
    }
    return;
  }
  const float* src = y ? biw : fiw;
  unsigned short* dst = inw16 + (y ? 593920 : 0);
  if (i < 148480) {
    float4 v = ((const float4*)src)[i];
    ushort4 o;
    o.x = f2bf(v.x); o.y = f2bf(v.y); o.z = f2bf(v.z); o.w = f2bf(v.w);
    ((ushort4*)dst)[i] = o;
  }
}

// ---------------- W_f = P1 @ ow_f, W_b = P2 @ ow_b (fp32 acc -> bf16) ----------------
__global__ __launch_bounds__(256) void wprep_k(
    const float* __restrict__ pw, const float* __restrict__ fow,
    const float* __restrict__ bow, unsigned short* __restrict__ W16) {
  int k0 = blockIdx.x * 64, o0 = blockIdx.y * 32, dir = blockIdx.z;
  const float* ow = dir ? bow : fow;
  unsigned short* Wout = W16 + (size_t)dir * 262144;
  int tid = threadIdx.x;
  int oo = tid & 31, kg = tid >> 5;
  __shared__ float sP[32][33];
  __shared__ float sW[32][64];
  float acc[8] = {};
  for (int nc = 0; nc < 8; nc++) {
    int n0 = nc * 32;
    __syncthreads();
#pragma unroll
    for (int i = 0; i < 4; i++) {
      int idx = tid + i * 256;
      sP[idx >> 5][idx & 31] = pw[(size_t)(o0 + (idx >> 5)) * 512 + dir * 256 + n0 + (idx & 31)];
    }
#pragma unroll
    for (int i = 0; i < 8; i++) {
      int idx = tid + i * 256;
      sW[idx >> 6][idx & 63] = ow[(size_t)(n0 + (idx >> 6)) * 1024 + k0 + (idx & 63)];
    }
    __syncthreads();
#pragma unroll 8
    for (int nn = 0; nn < 32; nn++) {
      float p = sP[oo][nn];
      const float* wr_ = &sW[nn][kg * 8];
#pragma unroll
      for (int j = 0; j < 8; j++) acc[j] += p * wr_[j];
    }
  }
  unsigned short tmp[8];
#pragma unroll
  for (int j = 0; j < 8; j++) tmp[j] = f2bf(acc[j]);
  unsigned short* dst = &Wout[(size_t)(o0 + oo) * 1024 + k0 + kg * 8];
  *(ushort4*)dst       = *(ushort4*)&tmp[0];
  *(ushort4*)(dst + 4) = *(ushort4*)&tmp[4];
}

// ---------------- bf16 MFMA GEMM with global_load_lds staging ----------------
__global__ __launch_bounds__(256) void gemm2_k(
    const unsigned short* __restrict__ A, int lda, long sA,
    const unsigned short* __restrict__ B, int ldb, long sB,
    void* __restrict__ Cout, int ldc, long sC,
    int M, int N, int K, int flipsel, int obf) {
  int zb = blockIdx.z;
  A += (size_t)zb * sA;
  B += (size_t)zb * sB;
  int flip = flipsel ? (zb ? 2047 : 0) : 0;
  int m0 = blockIdx.y * 128, n0 = blockIdx.x * 128;
  __shared__ unsigned short As[4096];   // [128][32] linear
  __shared__ unsigned short Bs[4096];
  int tid = threadIdx.x;
  int lane = tid & 63, wid = tid >> 6;
  int wr = (wid >> 1) * 64, wc = (wid & 1) * 64;
  int fr = lane & 15, fq = lane >> 4;
  f32x4 acc[4][4] = {};
  for (int k0 = 0; k0 < K; k0 += 32) {
#pragma unroll
    for (int i = 0; i < 2; i++) {
      int idx = tid + i * 256;
      int r = idx >> 2, c8 = (idx & 3) * 8;
      int ldsoff = (i * 256 + wid * 64) * 8;
      gl_lds16(&A[(size_t)((m0 + r) ^ flip) * lda + k0 + c8], As + ldsoff);
      gl_lds16(&B[(size_t)(n0 + r) * ldb + k0 + c8], Bs + ldsoff);
    }
    __syncthreads();
    bf16x8 a[4], b[4];
#pragma unroll
    for (int m = 0; m < 4; m++) a[m] = *(const bf16x8*)&As[(wr + m * 16 + fr) * 32 + fq * 8];
#pragma unroll
    for (int n = 0; n < 4; n++) b[n] = *(const bf16x8*)&Bs[(wc + n * 16 + fr) * 32 + fq * 8];
#pragma unroll
    for (int m = 0; m < 4; m++)
#pragma unroll
      for (int n = 0; n < 4; n++)
        acc[m][n] = __builtin_amdgcn_mfma_f32_16x16x32_bf16(a[m], b[n], acc[m][n], 0, 0, 0);
    __syncthreads();
  }
  if (obf) {
    unsigned short* C16 = (unsigned short*)Cout + (size_t)zb * sC;
#pragma unroll
    for (int m = 0; m < 4; m++) {
      int row = m0 + wr + m * 16 + fq * 4;
#pragma unroll
      for (int n = 0; n < 4; n++) {
        int col = n0 + wc + n * 16 + fr;
        if (col < N) {
#pragma unroll
          for (int j = 0; j < 4; j++) C16[(size_t)(row + j) * ldc + col] = f2bf(acc[m][n][j]);
        }
      }
    }
  } else {
    float* C = (float*)Cout + (size_t)zb * sC;
#pragma unroll
    for (int m = 0; m < 4; m++) {
      int row = m0 + wr + m * 16 + fq * 4;
#pragma unroll
      for (int n = 0; n < 4; n++) {
        int col = n0 + wc + n * 16 + fr;
        if (col < N) {
#pragma unroll
          for (int j = 0; j < 4; j++) C[(size_t)(row + j) * ldc + col] = acc[m][n][j];
        }
      }
    }
  }
}

// ---------------- conv4 + silu + fused transpose outputs (32-l chunks) ----------------
__global__ __launch_bounds__(256) void convt_k(
    const float* __restrict__ fcw, const float* __restrict__ bcw,
    const float* __restrict__ fcb, const float* __restrict__ bcb,
    float* __restrict__ scr0, long DS,
    unsigned short* __restrict__ dtxt16, unsigned short* __restrict__ bt16) {
  int bx = blockIdx.x;
  int j = bx * 256 + threadIdx.x;
  int l0 = blockIdx.y * 32;
  int b = blockIdx.z & 1, dir = blockIdx.z >> 1, slot = blockIdx.z;
  float* scr = scr0 + (size_t)dir * DS;
  const unsigned short* zx16 = (const unsigned short*)(scr + S_ZX16);
  unsigned short* xp16 = (unsigned short*)(scr + S_XP16);
  const float* dtp = scr + S_DT;
  const float* cwp = (dir ? bcw : fcw) + j * 4;
  float c0 = cwp[0], c1 = cwp[1], c2 = cwp[2], c3 = cwp[3];
  float cb = (dir ? bcb : fcb)[j];
  size_t colz = 1024 + j;
  bool isX = (bx < 4);
  int h = j >> 6;
  float w0 = 0.f, w1 = 0.f, w2 = 0.f;
  if (l0 >= 3) {
    w0 = bf2f(zx16[(size_t)(b * 2048 + l0 - 3) * DPROJ + colz]);
    w1 = bf2f(zx16[(size_t)(b * 2048 + l0 - 2) * DPROJ + colz]);
    w2 = bf2f(zx16[(size_t)(b * 2048 + l0 - 1) * DPROJ + colz]);
  }
  bf16x8 rb[4];
#pragma unroll
  for (int li = 0; li < 32; li++) {
    int row = b * 2048 + l0 + li;
    float cur = bf2f(zx16[(size_t)row * DPROJ + colz]);
    float o = silu(cb + c0 * w0 + c1 * w1 + c2 * w2 + c3 * cur);
    xp16[(size_t)row * 1280 + j] = f2bf(o);
    float mult = isX ? dtp[(size_t)row * 16 + h] : 1.f;
    rb[li >> 3][li & 7] = (__bf16)(o * mult);
    w0 = w1; w1 = w2; w2 = cur;
  }
  unsigned short* base = nullptr;
  if (isX) {
    base = dtxt16 + ((size_t)(slot * 16 + h) * 64 + (j & 63)) * 2048 + l0;
  } else if (threadIdx.x < 128) {
    base = bt16 + ((size_t)slot * 128 + threadIdx.x) * 2048 + l0;
  }
  if (base) {
#pragma unroll
    for (int i = 0; i < 4; i++) *(bf16x8*)(base + i * 8) = rb[i];
  }
}

// ---------------- fused dt + softplus + A + per-chunk scan ----------------
__global__ __launch_bounds__(256) void dscan_k(
    const float* __restrict__ t,
    const float* __restrict__ fiw, const float* __restrict__ biw,
    const float* __restrict__ fdtb, const float* __restrict__ bdtb,
    const float* __restrict__ fAlog, const float* __restrict__ bAlog,
    float* __restrict__ scr0, long DS) {
  int h = blockIdx.x, c = blockIdx.y;
  int b = blockIdx.z & 1, dir = blockIdx.z >> 1;
  const float* in_w = dir ? biw : fiw;
  float dtbv = (dir ? bdtb : fdtb)[h];
  float alog = (dir ? bAlog : fAlog)[h];
  float* scr = scr0 + (size_t)dir * DS;
  int l = threadIdx.x;
  int row = b * 2048 + c * 256 + l;
  int flip = dir ? 2047 : 0;
  __shared__ float sw[256];
  __shared__ float buf0[256], buf1[256];
  sw[l] = in_w[(size_t)(2304 + h) * 256 + l];
  __syncthreads();
  const float4* t4 = (const float4*)(t + (size_t)(row ^ flip) * 256);
  const float4* w4 = (const float4*)sw;
  float s = 0.f;
#pragma unroll 8
  for (int k = 0; k < 64; k++) {
    float4 a = t4[k], w = w4[k];
    s += a.x * w.x + a.y * w.y + a.z * w.z + a.w * w.w;
  }
  float rawv = s + dtbv;
  float d = (rawv > 20.f) ? rawv : log1pf(expf(rawv));
  (scr + S_DT)[(size_t)row * 16 + h] = d;
  buf0[l] = -expf(alog) * d;
  __syncthreads();
  float* src = buf0;
  float* dst = buf1;
  for (int off = 1; off < 256; off <<= 1) {
    float v = src[l];
    if (l >= off) v += src[l - off];
    dst[l] = v;
    __syncthreads();
    float* tmp = src; src = dst; dst = tmp;
  }
  float scn = src[l];
  int chidx = (b * NCH + c) * NH + h;
  (scr + S_ACS)[(size_t)chidx * 256 + l] = scn;
  if (l == 255) (scr + S_TT)[chidx] = scn;
}

// ---------------- chunk states via MFMA: S[p=64][n-half=64] ----------------
__global__ __launch_bounds__(256) void states_mfma_k(
    float* __restrict__ scr0, long DS,
    const unsigned short* __restrict__ dtxt16, const unsigned short* __restrict__ bt16) {
  int h = blockIdx.x, c = blockIdx.y;
  int nh2 = blockIdx.z & 1, b = (blockIdx.z >> 1) & 1, dir = blockIdx.z >> 2;
  int slot = dir * 2 + b;
  float* scr = scr0 + (size_t)dir * DS;
  const float* Acs = scr + S_ACS;
  const float* Ttot = scr + S_TT;
  float* stout = scr + S_ST;
  int tid = threadIdx.x;
  int chidx = (b * NCH + c) * NH + h;
  size_t xtb = ((size_t)(slot * 16 + h) * 64) * 2048 + c * 256;
  size_t btb = ((size_t)slot * 128 + nh2 * 64) * 2048 + c * 256;
  __shared__ float sXs[256];
  __shared__ unsigned short At[64][40];
  __shared__ unsigned short Bt[64][40];
  {
    float a = Acs[(size_t)chidx * 256 + tid];
    float Tt = Ttot[chidx];
    sXs[tid] = __expf(Tt - a);
  }
  __syncthreads();
  int lane = tid & 63, w = tid >> 6;
  int fr = lane & 15, fq = lane >> 4;
  int sp = tid >> 2, sk = (tid & 3) * 8;
  f32x4 acc[4] = {};
  for (int k0 = 0; k0 < 256; k0 += 32) {
    {
      ushort4 xa = *(const ushort4*)&dtxt16[xtb + (size_t)sp * 2048 + k0 + sk];
      ushort4 xb = *(const ushort4*)&dtxt16[xtb + (size_t)sp * 2048 + k0 + sk + 4];
      float4 w0 = *(const float4*)&sXs[k0 + sk];
      float4 w1 = *(const float4*)&sXs[k0 + sk + 4];
      unsigned short tmp[8];
      tmp[0] = f2bf(bf2f(xa.x) * w0.x); tmp[1] = f2bf(bf2f(xa.y) * w0.y);
      tmp[2] = f2bf(bf2f(xa.z) * w0.z); tmp[3] = f2bf(bf2f(xa.w) * w0.w);
      tmp[4] = f2bf(bf2f(xb.x) * w1.x); tmp[5] = f2bf(bf2f(xb.y) * w1.y);
      tmp[6] = f2bf(bf2f(xb.z) * w1.z); tmp[7] = f2bf(bf2f(xb.w) * w1.w);
      *(ushort4*)&At[sp][sk]     = *(ushort4*)&tmp[0];
      *(ushort4*)&At[sp][sk + 4] = *(ushort4*)&tmp[4];
      *(bf16x8*)&Bt[sp][sk] = *(const bf16x8*)&bt16[btb + (size_t)sp * 2048 + k0 + sk];
    }
    __syncthreads();
    bf16x8 bb = *(const bf16x8*)&Bt[w * 16 + fr][fq * 8];
#pragma unroll
    for (int m = 0; m < 4; m++) {
      bf16x8 a = *(const bf16x8*)&At[m * 16 + fr][fq * 8];
      acc[m] = __builtin_amdgcn_mfma_f32_16x16x32_bf16(a, bb, acc[m], 0, 0, 0);
    }
    __syncthreads();
  }
#pragma unroll
  for (int m = 0; m < 4; m++) {
    int p = m * 16 + fq * 4;
    int nn = nh2 * 64 + w * 16 + fr;
#pragma unroll
    for (int j = 0; j < 4; j++)
      stout[(size_t)chidx * 8192 + (size_t)(p + j) * 128 + nn] = acc[m][j];
  }
}

// ---------------- inter-chunk recurrence (Sin -> bf16) ----------------
__global__ __launch_bounds__(256) void recur_k(float* __restrict__ scr0, long DS) {
  int h = blockIdx.x;
  int b = blockIdx.y & 1, dir = blockIdx.y >> 1;
  float* scr = scr0 + (size_t)dir * DS;
  const float* st = scr + S_ST;
  const float* Ttot = scr + S_TT;
  unsigned short* Sin16 = (unsigned short*)(scr + S_SIN);
  int e0 = threadIdx.x * 32;
  float4 s[8];
#pragma unroll
  for (int j = 0; j < 8; j++) s[j] = make_float4(0.f, 0.f, 0.f, 0.f);
  for (int c = 0; c < 8; c++) {
    int chidx = (b * NCH + c) * NH + h;
    size_t base = (size_t)chidx * 8192 + e0;
    const float4* si = (const float4*)(st + base);
    float dec = __expf(Ttot[chidx]);
#pragma unroll
    for (int j = 0; j < 8; j++) {
      ushort4 o;
      o.x = f2bf(s[j].x); o.y = f2bf(s[j].y); o.z = f2bf(s[j].z); o.w = f2bf(s[j].w);
      *(ushort4*)&Sin16[base + j * 4] = o;
      float4 v = si[j];
      s[j].x = s[j].x * dec + v.x; s[j].y = s[j].y * dec + v.y;
      s[j].z = s[j].z * dec + v.z; s[j].w = s[j].w * dec + v.w;
    }
  }
}

// ---------------- fused Y_diag + Y_off, flash-style, bf16 out ----------------
__global__ __launch_bounds__(256) void ydo2_k(
    float* __restrict__ scr0, long DS, const unsigned short* __restrict__ dtxt16) {
  int h = blockIdx.x;
  int cy = blockIdx.y;
  int c = cy >> 2, lt = cy & 3;
  int b = blockIdx.z & 1, dir = blockIdx.z >> 1;
  int slot = dir * 2 + b;
  float* scr = scr0 + (size_t)dir * DS;
  const float* Acs = scr + S_ACS;
  const unsigned short* xp16 = (const unsigned short*)(scr + S_XP16);
  const unsigned short* Sin16 = (const unsigned short*)(scr + S_SIN);
  unsigned short* yhp16 = (unsigned short*)(scr + S_YHP16);
  int tid = threadIdx.x;
  int lane = tid & 63, w = tid >> 6;
  int fr = lane & 15, fq = lane >> 4;
  int row0 = b * 2048 + c * 256;
  int chidx = (b * NCH + c) * NH + h;
  int l0 = lt * 64;
  size_t xtb = ((size_t)(slot * 16 + h) * 64) * 2048 + c * 256;

  __shared__ unsigned short sBS[64][136];
  __shared__ unsigned short sXt[64][72];
  __shared__ unsigned short sP[64][72];
  __shared__ float sA[64], sAs[64];

  bf16x8 af[4];
#pragma unroll
  for (int k = 0; k < 4; k++)
    af[k] = *(const bf16x8*)&xp16[(size_t)(row0 + l0 + w * 16 + fr) * 1280 + 1152 + k * 32 + fq * 8];

#pragma unroll
  for (int i = 0; i < 4; i++) {
    int chunk = tid + i * 256;
    int p = chunk >> 4, n8 = (chunk & 15) * 8;
    *(bf16x8*)&sBS[p][n8] = *(const bf16x8*)&Sin16[(size_t)chidx * 8192 + p * 128 + n8];
  }
  if (tid < 64) sA[tid] = Acs[(size_t)chidx * 256 + l0 + tid];
  __syncthreads();

  f32x4 acc[4] = {};
#pragma unroll
  for (int n = 0; n < 4; n++) {
#pragma unroll
    for (int k = 0; k < 4; k++) {
      bf16x8 bb = *(const bf16x8*)&sBS[n * 16 + fr][k * 32 + fq * 8];
      acc[n] = __builtin_amdgcn_mfma_f32_16x16x32_bf16(af[k], bb, acc[n], 0, 0, 0);
    }
  }
  {
    int lrow = w * 16 + fq * 4;
    float el[4];
#pragma unroll
    for (int j = 0; j < 4; j++) el[j] = __expf(sA[lrow + j]);
#pragma unroll
    for (int n = 0; n < 4; n++)
#pragma unroll
      for (int j = 0; j < 4; j++) acc[n][j] *= el[j];
  }

  for (int st = 0; st <= lt; st++) {
    __syncthreads();
    int srow0 = row0 + st * 64;
#pragma unroll
    for (int i = 0; i < 4; i++) {
      int chunk = tid + i * 256;
      int r = chunk >> 4, c8 = (chunk & 15) * 8;
      *(bf16x8*)&sBS[r][c8] = *(const bf16x8*)&xp16[(size_t)(srow0 + r) * 1280 + 1024 + c8];
    }
#pragma unroll
    for (int i = 0; i < 2; i++) {
      int chunk = tid + i * 256;
      int p = chunk >> 3, s8 = (chunk & 7) * 8;
      *(bf16x8*)&sXt[p][s8] = *(const bf16x8*)&dtxt16[xtb + (size_t)p * 2048 + st * 64 + s8];
    }
    if (tid < 64) sAs[tid] = Acs[(size_t)chidx * 256 + st * 64 + tid];
    __syncthreads();

    f32x4 cb[4] = {};
#pragma unroll
    for (int n = 0; n < 4; n++) {
#pragma unroll
      for (int k = 0; k < 4; k++) {
        bf16x8 bb = *(const bf16x8*)&sBS[n * 16 + fr][k * 32 + fq * 8];
        cb[n] = __builtin_amdgcn_mfma_f32_16x16x32_bf16(af[k], bb, cb[n], 0, 0, 0);
      }
    }
    {
      int lrow = w * 16 + fq * 4;
      float al[4];
#pragma unroll
      for (int j = 0; j < 4; j++) al[j] = sA[lrow + j];
      bool full = (st < lt);
#pragma unroll
      for (int n = 0; n < 4; n++) {
        int srow = n * 16 + fr;
        float as_ = sAs[srow];
#pragma unroll
        for (int j = 0; j < 4; j++) {
          float v = (full || srow <= lrow + j) ? cb[n][j] * __expf(al[j] - as_) : 0.f;
          sP[lrow + j][srow] = f2bf(v);
        }
      }
    }
#pragma unroll
    for (int k2 = 0; k2 < 2; k2++) {
      bf16x8 pa = *(const bf16x8*)&sP[w * 16 + fr][k2 * 32 + fq * 8];
#pragma unroll
      for (int n = 0; n < 4; n++) {
        bf16x8 bb = *(const bf16x8*)&sXt[n * 16 + fr][k2 * 32 + fq * 8];
        acc[n] = __builtin_amdgcn_mfma_f32_16x16x32_bf16(pa, bb, acc[n], 0, 0, 0);
      }
    }
  }

#pragma unroll
  for (int n = 0; n < 4; n++) {
    int p = n * 16 + fr;
#pragma unroll
    for (int j = 0; j < 4; j++) {
      int row = row0 + l0 + w * 16 + fq * 4 + j;
      yhp16[(size_t)row * 1024 + h * 64 + p] = f2bf(acc[n][j]);
    }
  }
}

// ---------------- gate + x*D + RMS norm, all bf16, in place ----------------
__global__ __launch_bounds__(256) void gate_rms_k(
    float* __restrict__ scr0, long DS,
    const float* __restrict__ fD, const float* __restrict__ bD,
    const float* __restrict__ fnw, const float* __restrict__ bnw) {
  int row = blockIdx.x;
  int dir = blockIdx.y;
  float* scr = scr0 + (size_t)dir * DS;
  unsigned short* yhp16 = (unsigned short*)(scr + S_YHP16);
  const unsigned short* xp16 = (const unsigned short*)(scr + S_XP16);
  const unsigned short* zx16 = (const unsigned short*)(scr + S_ZX16);
  const float* Dv = dir ? bD : fD;
  const float* nw = dir ? bnw : fnw;
  float g[4];
  float ss = 0.f;
#pragma unroll
  for (int k = 0; k < 4; k++) {
    int i = threadIdx.x + k * 256;
    int h = i >> 6;
    float y = bf2f(yhp16[(size_t)row * 1024 + i]) +
              bf2f(xp16[(size_t)row * 1280 + i]) * Dv[h];
    float z = bf2f(zx16[(size_t)row * DPROJ + i]);
    float gg = y * silu(z);
    ss += gg * gg;
    g[k] = gg;
  }
  for (int o = 32; o > 0; o >>= 1) ss += __shfl_down(ss, o);
  __shared__ float red[5];
  int wid = threadIdx.x >> 6;
  if ((threadIdx.x & 63) == 0) red[wid] = ss;
  __syncthreads();
  if (threadIdx.x == 0) red[4] = red[0] + red[1] + red[2] + red[3];
  __syncthreads();
  float rstd = rsqrtf(red[4] / 1024.f + 1e-5f);
#pragma unroll
  for (int k = 0; k < 4; k++) {
    int i = threadIdx.x + k * 256;
    yhp16[(size_t)row * 1024 + i] = f2bf(g[k] * rstd * nw[i]);
  }
}

// ---------------- fused output mega-GEMM, split-K=3 ----------------
// pr[row,o] = [yhp_f[row] | yhp_b[row^2047] | t16[row]] (K=2304) @ [Wf|Wb|tw][o]^T
__global__ __launch_bounds__(256) void gemm_f2_k(
    const unsigned short* __restrict__ yhpf16, const unsigned short* __restrict__ yhpb16,
    const unsigned short* __restrict__ t16, const unsigned short* __restrict__ W16,
    float* __restrict__ prp) {
  int n0 = blockIdx.x * 64, m0 = blockIdx.y * 64, kpart = blockIdx.z;
  int kbase = kpart * 768;
  __shared__ unsigned short As[2048];   // [64][32] linear
  __shared__ unsigned short Bs[2048];
  int tid = threadIdx.x;
  int lane = tid & 63, wid = tid >> 6;
  int wr = (wid >> 1) * 32, wc = (wid & 1) * 32;
  int fr = lane & 15, fq = lane >> 4;
  int r = tid >> 2, c8 = (tid & 3) * 8;
  f32x4 acc[2][2] = {};
  for (int ki = 0; ki < 24; ki++) {
    int k0 = kbase + ki * 32;
    int gk = k0 + c8;
    {
      const unsigned short* asrc;
      const unsigned short* bsrc;
      int gm = m0 + r;
      int o = n0 + r;
      if (gk < 1024) {
        asrc = yhpf16 + (size_t)gm * 1024 + gk;
        bsrc = W16 + (size_t)o * 1024 + gk;
      } else if (gk < 2048) {
        asrc = yhpb16 + (size_t)(gm ^ 2047) * 1024 + (gk - 1024);
        bsrc = W16 + 262144 + (size_t)o * 1024 + (gk - 1024);
      } else {
        asrc = t16 + (size_t)gm * 256 + (gk - 2048);
        bsrc = W16 + 524288 + (size_t)o * 256 + (gk - 2048);
      }
      int ldsoff = wid * 512;
      gl_lds16(asrc, As + ldsoff);
      gl_lds16(bsrc, Bs + ldsoff);
    }
    __syncthreads();
    bf16x8 a[2], b[2];
#pragma unroll
    for (int m = 0; m < 2; m++) a[m] = *(const bf16x8*)&As[(wr + m * 16 + fr) * 32 + fq * 8];
#pragma unroll
    for (int n = 0; n < 2; n++) b[n] = *(const bf16x8*)&Bs[(wc + n * 16 + fr) * 32 + fq * 8];
#pragma unroll
    for (int m = 0; m < 2; m++)
#pragma unroll
      for (int n = 0; n < 2; n++)
        acc[m][n] = __builtin_amdgcn_mfma_f32_16x16x32_bf16(a[m], b[n], acc[m][n], 0, 0, 0);
    __syncthreads();
  }
  float* C = prp + (size_t)kpart * 1048576;
#pragma unroll
  for (int m = 0; m < 2; m++) {
    int row = m0 + wr + m * 16 + fq * 4;
#pragma unroll
    for (int n = 0; n < 2; n++) {
      int col = n0 + wc + n * 16 + fr;
#pragma unroll
      for (int j = 0; j < 4; j++) C[(size_t)(row + j) * 256 + col] = acc[m][n][j];
    }
  }
}

// ---------------- out = x + (pr0+pr1+pr2)^T + proj_b ----------------
__global__ __launch_bounds__(256) void final_add3_k(const float* __restrict__ x,
                                                    const float* __restrict__ prp,
                                                    const float* __restrict__ pb,
                                                    float* __restrict__ out) {
  int l0 = blockIdx.x * 32, c0 = blockIdx.y * 32, b = blockIdx.z;
  int tx = threadIdx.x & 31, ty = threadIdx.x >> 5;
  __shared__ float tile[32][33];
#pragma unroll
  for (int i = 0; i < 4; i++) {
    int ll = ty + i * 8;
    size_t idx = (size_t)(b * 2048 + l0 + ll) * 256 + c0 + tx;
    tile[ll][tx] = prp[idx] + prp[idx + 1048576] + prp[idx + 2097152];
  }
  __syncthreads();
#pragma unroll
  for (int i = 0; i < 4; i++) {
    int ch = c0 + ty + i * 8;
    size_t o = (size_t)b * 524288 + (size_t)ch * 2048 + l0 + tx;
    out[o] = x[o] + tile[tx][ty + i * 8] + pb[ch];
  }
}

}  // namespace

extern "C" void kernel_launch(void* const* d_in, const int* in_sizes, int n_in,
                              void* d_out, int out_size, void* d_ws, size_t ws_size,
                              hipStream_t stream) {
  (void)in_sizes; (void)n_in; (void)out_size; (void)ws_size;
  const float* x      = (const float*)d_in[0];
  const float* gn_w   = (const float*)d_in[1];
  const float* gn_b   = (const float*)d_in[2];
  const float* proj_w = (const float*)d_in[3];
  const float* proj_b = (const float*)d_in[4];
  const float* fiw  = (const float*)d_in[5];
  const float* fcw  = (const float*)d_in[6];
  const float* fcb  = (const float*)d_in[7];
  const float* fdtb = (const float*)d_in[8];
  const float* fAl  = (const float*)d_in[9];
  const float* fD   = (const float*)d_in[10];
  const float* fnw  = (const float*)d_in[11];
  const float* fow  = (const float*)d_in[12];
  const float* biw  = (const float*)d_in[13];
  const float* bcw  = (const float*)d_in[14];
  const float* bcb  = (const float*)d_in[15];
  const float* bdtb = (const float*)d_in[16];
  const float* bAl  = (const float*)d_in[17];
  const float* bD   = (const float*)d_in[18];
  const float* bnw  = (const float*)d_in[19];
  const float* bow  = (const float*)d_in[20];
  float* out = (float*)d_out;
  float* ws  = (float*)d_ws;
  float* scr0 = ws + F_SCR0;
  const long DS = (long)SZ_SCR;
  const long DSU = DS * 2;

  unsigned short* t16     = (unsigned short*)(ws + F_BF);
  unsigned short* inw16   = t16 + 1048576;
  unsigned short* W16     = inw16 + 1187840;   // Wf(262144) | Wb(262144) | tw(65536)
  unsigned short* dtxt16  = W16 + 655360;
  unsigned short* bt16    = dtxt16 + 8388608;
  unsigned short* zx16    = (unsigned short*)(scr0 + S_ZX16);
  unsigned short* yhpf16  = (unsigned short*)(scr0 + S_YHP16);
  unsigned short* yhpb16  = (unsigned short*)(scr0 + DS + S_YHP16);
  float* prp = ws + F_PRP;

  // groupnorm + transpose
  stats_partial_k<<<dim3(64, 2), 256, 0, stream>>>(x, ws + F_PART);
  stats_final_k<<<2, 64, 0, stream>>>(ws + F_PART, ws + F_STATS);
  normt2_k<<<dim3(64, 8, 2), 256, 0, stream>>>(x, gn_w, gn_b, ws + F_STATS, ws + F_T, t16);
  // in_proj weights -> bf16; tw = P1+P2
  cvtw_k<<<dim3(580, 3), 256, 0, stream>>>(fiw, biw, proj_w, inw16, W16);
  // W_f = P1 @ ow_f, W_b = P2 @ ow_b
  wprep_k<<<dim3(16, 8, 2), 256, 0, stream>>>(proj_w, fow, bow, W16);

  // in_proj (bf16 out), both dirs batched, async-LDS staging
  gemm2_k<<<dim3(19, 32, 2), 256, 0, stream>>>(
      t16, 256, 0, inw16, 256, 593920L, zx16, DPROJ, DSU, 4096, DPROJ, 256, 1, 1);
  // dt + scan (fp32)
  dscan_k<<<dim3(NH, NCH, 4), 256, 0, stream>>>(
      ws + F_T, fiw, biw, fdtb, bdtb, fAl, bAl, scr0, DS);
  // conv + silu + fused dtX^T / B^T transpose (32-l chunks)
  convt_k<<<dim3(5, 64, 4), 256, 0, stream>>>(fcw, bcw, fcb, bcb, scr0, DS, dtxt16, bt16);
  // chunk states
  states_mfma_k<<<dim3(NH, NCH, 8), 256, 0, stream>>>(scr0, DS, dtxt16, bt16);
  // inter-chunk recurrence (Sin -> bf16)
  recur_k<<<dim3(NH, 4), 256, 0, stream>>>(scr0, DS);
  // fused Y_diag + Y_off
  ydo2_k<<<dim3(NH, NCH * 4, 4), 256, 0, stream>>>(scr0, DS, dtxt16);
  // gate + RMS norm (in place on yhp16)
  gate_rms_k<<<dim3(4096, 2), 256, 0, stream>>>(scr0, DS, fD, bD, fnw, bnw);
  // fused output mega-GEMM, split-K=3
  gemm_f2_k<<<dim3(4, 64, 3), 256, 0, stream>>>(yhpf16, yhpb16, t16, W16, prp);
  // out = x + sum(pr)^T + proj_b
  final_add3_k<<<dim3(64, 8, 2), 256, 0, stream>>>(x, prp, proj_b, out);
}

// Round 11
// 291.524 us; speedup vs baseline: 1.1958x; 1.1085x over previous
//
#include <hip/hip_runtime.h>
#include <math.h>

namespace {

constexpr int NH    = 16;
constexpr int DPROJ = 2320;
constexpr int NCH   = 8;

// ---- workspace layout (float offsets) ----
constexpr size_t F_STATS = 0;                  // 4 (unused now)
constexpr size_t F_PART  = 4;                  // 256
constexpr size_t F_T     = 260;                // (B*L,256) fp32
constexpr size_t SZ_T    = 2ull * 2048 * 256;  // 1048576
constexpr size_t F_PRP   = F_T + SZ_T;         // 3 split-K partials, each SZ_T fp32
constexpr size_t F_SCR0  = F_PRP + 3 * SZ_T;   // per-dir scratch base (x2)

// per-direction scratch (float offsets inside scr); bf16 tensors cast to ushort*
constexpr size_t S_ZX16  = 0;                  // (B*L,2320) bf16
constexpr size_t S_XP16  = 4751360;            // (B*L,1280) bf16
constexpr size_t S_DT    = S_XP16 + 2621440;   // (B*L,16) fp32
constexpr size_t S_ACS   = S_DT + 65536;
constexpr size_t S_TT    = S_ACS + 65536;
constexpr size_t S_ST    = S_TT + 256;         // chunk states fp32
constexpr size_t S_SIN   = S_ST + 2097152;     // Sin bf16 (ushort overlay)
constexpr size_t S_YHP16 = S_SIN + 2097152;    // (B*L,1024) bf16
constexpr size_t SZ_SCR  = S_YHP16 + 2097152;

constexpr size_t F_BF = F_SCR0 + 2 * SZ_SCR;   // ushort region base

typedef __bf16 bf16x8 __attribute__((ext_vector_type(8)));
typedef float  f32x4  __attribute__((ext_vector_type(4)));

__device__ __forceinline__ float silu(float v) { return v / (1.f + expf(-v)); }

__device__ __forceinline__ unsigned short f2bf(float f) {
  unsigned int u = __float_as_uint(f);
  return (unsigned short)((u + 0x7fffu + ((u >> 16) & 1u)) >> 16);
}
__device__ __forceinline__ float bf2f(unsigned short u) {
  return __uint_as_float((unsigned int)u << 16);
}

// async global->LDS, 16B per lane (dest = wave-uniform base + lane*16)
__device__ __forceinline__ void gl_lds16(const unsigned short* g, unsigned short* l) {
  typedef __attribute__((address_space(1))) const unsigned int gq;
  typedef __attribute__((address_space(3))) unsigned int lq;
  __builtin_amdgcn_global_load_lds((gq*)g, (lq*)l, 16, 0, 0);
}

// ---------------- merged prep: stats_partial (128) | cvtw (1740) | wprep (256) ----------------
__global__ __launch_bounds__(256) void prep_k(
    const float* __restrict__ x, float* __restrict__ part,
    const float* __restrict__ fiw, const float* __restrict__ biw,
    const float* __restrict__ pw,
    const float* __restrict__ fow, const float* __restrict__ bow,
    unsigned short* __restrict__ inw16, unsigned short* __restrict__ W16) {
  __shared__ float smem[3104];   // union: stats(8) | wprep sP(1056)+sW(2048)
  int flat = blockIdx.x;
  int tid = threadIdx.x;
  if (flat < 128) {
    // ---- stats partial ----
    int seg = flat & 63, b = flat >> 6;
    const float4* base = (const float4*)(x + (size_t)b * 524288 + (size_t)seg * 8192);
    float s = 0.f, q = 0.f;
#pragma unroll
    for (int i = 0; i < 8; i++) {
      float4 v = base[tid + i * 256];
      s += v.x + v.y + v.z + v.w;
      q += v.x * v.x + v.y * v.y + v.z * v.z + v.w * v.w;
    }
    for (int o = 32; o > 0; o >>= 1) { s += __shfl_down(s, o); q += __shfl_down(q, o); }
    int wid = tid >> 6;
    if ((tid & 63) == 0) { smem[wid] = s; smem[4 + wid] = q; }
    __syncthreads();
    if (tid == 0) {
      part[(b * 64 + seg) * 2]     = smem[0] + smem[1] + smem[2] + smem[3];
      part[(b * 64 + seg) * 2 + 1] = smem[4] + smem[5] + smem[6] + smem[7];
    }
  } else if (flat < 128 + 1740) {
    // ---- weight converts ----
    int f = flat - 128;
    int y = f / 580, xb = f - y * 580;
    int i = xb * 256 + tid;
    if (y == 2) {
      if (i < 16384) {
        int o = i >> 6, c4 = i & 63;
        float4 a = ((const float4*)pw)[(size_t)o * 128 + c4];
        float4 b = ((const float4*)pw)[(size_t)o * 128 + 64 + c4];
        ushort4 r;
        r.x = f2bf(a.x + b.x); r.y = f2bf(a.y + b.y);
        r.z = f2bf(a.z + b.z); r.w = f2bf(a.w + b.w);
        ((ushort4*)(W16 + 524288))[i] = r;
      }
    } else {
      const float* src = y ? biw : fiw;
      unsigned short* dst = inw16 + (y ? 593920 : 0);
      if (i < 148480) {
        float4 v = ((const float4*)src)[i];
        ushort4 o;
        o.x = f2bf(v.x); o.y = f2bf(v.y); o.z = f2bf(v.z); o.w = f2bf(v.w);
        ((ushort4*)dst)[i] = o;
      }
    }
  } else {
    // ---- wprep: W_dir = P_dir @ ow_dir ----
    int f = flat - 1868;
    int dir = f >> 7;
    int rest = f & 127;
    int k0 = (rest >> 3) * 64, o0 = (rest & 7) * 32;
    const float* ow = dir ? bow : fow;
    unsigned short* Wout = W16 + (size_t)dir * 262144;
    int oo = tid & 31, kg = tid >> 5;
    float* sP = smem;            // [32][33]
    float* sW = smem + 1056;     // [32][64]
    float acc[8] = {};
    for (int nc = 0; nc < 8; nc++) {
      int n0 = nc * 32;
      __syncthreads();
#pragma unroll
      for (int i = 0; i < 4; i++) {
        int idx = tid + i * 256;
        sP[(idx >> 5) * 33 + (idx & 31)] =
            pw[(size_t)(o0 + (idx >> 5)) * 512 + dir * 256 + n0 + (idx & 31)];
      }
#pragma unroll
      for (int i = 0; i < 8; i++) {
        int idx = tid + i * 256;
        sW[(idx >> 6) * 64 + (idx & 63)] =
            ow[(size_t)(n0 + (idx >> 6)) * 1024 + k0 + (idx & 63)];
      }
      __syncthreads();
#pragma unroll 8
      for (int nn = 0; nn < 32; nn++) {
        float p = sP[oo * 33 + nn];
        const float* wr_ = &sW[nn * 64 + kg * 8];
#pragma unroll
        for (int j = 0; j < 8; j++) acc[j] += p * wr_[j];
      }
    }
    unsigned short tmp[8];
#pragma unroll
    for (int j = 0; j < 8; j++) tmp[j] = f2bf(acc[j]);
    unsigned short* dst = &Wout[(size_t)(o0 + oo) * 1024 + k0 + kg * 8];
    *(ushort4*)dst       = *(ushort4*)&tmp[0];
    *(ushort4*)(dst + 4) = *(ushort4*)&tmp[4];
  }
}

// ---------------- normalize + transpose, inline stats-final ----------------
__global__ __launch_bounds__(256) void normt2_k(const float* __restrict__ x,
                                                const float* __restrict__ gw,
                                                const float* __restrict__ gb,
                                                const float* __restrict__ part,
                                                float* __restrict__ t,
                                                unsigned short* __restrict__ t16) {
  int l0 = blockIdx.x * 32, c0 = blockIdx.y * 32, b = blockIdx.z;
  int tx = threadIdx.x & 31, ty = threadIdx.x >> 5;
  __shared__ float tile[32][33];
  __shared__ float sstat[2];
  if (threadIdx.x < 64) {
    float s = part[(b * 64 + threadIdx.x) * 2];
    float q = part[(b * 64 + threadIdx.x) * 2 + 1];
    for (int o = 32; o > 0; o >>= 1) { s += __shfl_down(s, o); q += __shfl_down(q, o); }
    if (threadIdx.x == 0) {
      float mu  = s / 524288.f;
      float var = q / 524288.f - mu * mu;
      sstat[0] = mu;
      sstat[1] = rsqrtf(var + 1.1920929e-07f);
    }
  }
  __syncthreads();
  float mu = sstat[0], rstd = sstat[1];
#pragma unroll
  for (int i = 0; i < 4; i++) {
    int c = c0 + ty + i * 8;
    float v = x[(size_t)b * 524288 + (size_t)c * 2048 + l0 + tx];
    tile[ty + i * 8][tx] = (v - mu) * rstd * gw[c] + gb[c];
  }
  __syncthreads();
#pragma unroll
  for (int i = 0; i < 4; i++) {
    int ll = ty + i * 8;
    size_t o = (size_t)(b * 2048 + l0 + ll) * 256 + c0 + tx;
    float v = tile[tx][ll];
    t[o] = v;
    t16[o] = f2bf(v);
  }
}

// ---------------- co-launch: in_proj MFMA GEMM (1216) | dscan (512) ----------------
__global__ __launch_bounds__(256) void inproj_dscan_k(
    const unsigned short* __restrict__ t16, const float* __restrict__ t,
    const unsigned short* __restrict__ inw16,
    const float* __restrict__ fiw, const float* __restrict__ biw,
    const float* __restrict__ fdtb, const float* __restrict__ bdtb,
    const float* __restrict__ fAl, const float* __restrict__ bAl,
    float* __restrict__ scr0, long DS, unsigned short* __restrict__ zx16_0) {
  __shared__ unsigned short As[4096];   // union: gemm A | dscan sw(f32)
  __shared__ unsigned short Bs[4096];   // union: gemm B | dscan buf0/buf1(f32)
  int flat = blockIdx.x;
  int tid = threadIdx.x;
  if (flat < 1216) {
    int zb = flat / 608;
    int rem = flat - zb * 608;
    int mb = rem / 19, nb = rem - (rem / 19) * 19;
    int m0 = mb * 128, n0 = nb * 128;
    int flip = zb ? 2047 : 0;
    const unsigned short* A = t16;
    const unsigned short* B = inw16 + (size_t)zb * 593920;
    int lane = tid & 63, wid = tid >> 6;
    int wr = (wid >> 1) * 64, wc = (wid & 1) * 64;
    int fr = lane & 15, fq = lane >> 4;
    f32x4 acc[4][4] = {};
    for (int k0 = 0; k0 < 256; k0 += 32) {
#pragma unroll
      for (int i = 0; i < 2; i++) {
        int idx = tid + i * 256;
        int r = idx >> 2, c8 = (idx & 3) * 8;
        int ldsoff = (i * 256 + wid * 64) * 8;
        gl_lds16(&A[(size_t)((m0 + r) ^ flip) * 256 + k0 + c8], As + ldsoff);
        gl_lds16(&B[(size_t)(n0 + r) * 256 + k0 + c8], Bs + ldsoff);
      }
      __syncthreads();
      bf16x8 a[4], b[4];
#pragma unroll
      for (int m = 0; m < 4; m++) a[m] = *(const bf16x8*)&As[(wr + m * 16 + fr) * 32 + fq * 8];
#pragma unroll
      for (int n = 0; n < 4; n++) b[n] = *(const bf16x8*)&Bs[(wc + n * 16 + fr) * 32 + fq * 8];
#pragma unroll
      for (int m = 0; m < 4; m++)
#pragma unroll
        for (int n = 0; n < 4; n++)
          acc[m][n] = __builtin_amdgcn_mfma_f32_16x16x32_bf16(a[m], b[n], acc[m][n], 0, 0, 0);
      __syncthreads();
    }
    unsigned short* C16 = zx16_0 + (size_t)zb * (2 * DS);
#pragma unroll
    for (int m = 0; m < 4; m++) {
      int row = m0 + wr + m * 16 + fq * 4;
#pragma unroll
      for (int n = 0; n < 4; n++) {
        int col = n0 + wc + n * 16 + fr;
        if (col < DPROJ) {
#pragma unroll
          for (int j = 0; j < 4; j++) C16[(size_t)(row + j) * DPROJ + col] = f2bf(acc[m][n][j]);
        }
      }
    }
  } else {
    int f = flat - 1216;
    int h = f & 15, c = (f >> 4) & 7, z = f >> 7;
    int b = z & 1, dir = z >> 1;
    const float* in_w = dir ? biw : fiw;
    float dtbv = (dir ? bdtb : fdtb)[h];
    float alog = (dir ? bAl : fAl)[h];
    float* scr = scr0 + (size_t)dir * DS;
    int l = tid;
    int row = b * 2048 + c * 256 + l;
    int flip = dir ? 2047 : 0;
    float* sw = (float*)As;
    float* buf0 = (float*)Bs;
    float* buf1 = buf0 + 256;
    sw[l] = in_w[(size_t)(2304 + h) * 256 + l];
    __syncthreads();
    const float4* t4 = (const float4*)(t + (size_t)(row ^ flip) * 256);
    const float4* w4 = (const float4*)sw;
    float s = 0.f;
#pragma unroll 8
    for (int k = 0; k < 64; k++) {
      float4 a = t4[k], w = w4[k];
      s += a.x * w.x + a.y * w.y + a.z * w.z + a.w * w.w;
    }
    float rawv = s + dtbv;
    float d = (rawv > 20.f) ? rawv : log1pf(expf(rawv));
    (scr + S_DT)[(size_t)row * 16 + h] = d;
    buf0[l] = -expf(alog) * d;
    __syncthreads();
    float* src = buf0;
    float* dst = buf1;
    for (int off = 1; off < 256; off <<= 1) {
      float v = src[l];
      if (l >= off) v += src[l - off];
      dst[l] = v;
      __syncthreads();
      float* tmp = src; src = dst; dst = tmp;
    }
    float scn = src[l];
    int chidx = (b * NCH + c) * NH + h;
    (scr + S_ACS)[(size_t)chidx * 256 + l] = scn;
    if (l == 255) (scr + S_TT)[chidx] = scn;
  }
}

// ---------------- conv4 + silu + fused transpose outputs (32-l chunks) ----------------
__global__ __launch_bounds__(256) void convt_k(
    const float* __restrict__ fcw, const float* __restrict__ bcw,
    const float* __restrict__ fcb, const float* __restrict__ bcb,
    float* __restrict__ scr0, long DS,
    unsigned short* __restrict__ dtxt16, unsigned short* __restrict__ bt16) {
  int bx = blockIdx.x;
  int j = bx * 256 + threadIdx.x;
  int l0 = blockIdx.y * 32;
  int b = blockIdx.z & 1, dir = blockIdx.z >> 1, slot = blockIdx.z;
  float* scr = scr0 + (size_t)dir * DS;
  const unsigned short* zx16 = (const unsigned short*)(scr + S_ZX16);
  unsigned short* xp16 = (unsigned short*)(scr + S_XP16);
  const float* dtp = scr + S_DT;
  const float* cwp = (dir ? bcw : fcw) + j * 4;
  float c0 = cwp[0], c1 = cwp[1], c2 = cwp[2], c3 = cwp[3];
  float cb = (dir ? bcb : fcb)[j];
  size_t colz = 1024 + j;
  bool isX = (bx < 4);
  int h = j >> 6;
  float w0 = 0.f, w1 = 0.f, w2 = 0.f;
  if (l0 >= 3) {
    w0 = bf2f(zx16[(size_t)(b * 2048 + l0 - 3) * DPROJ + colz]);
    w1 = bf2f(zx16[(size_t)(b * 2048 + l0 - 2) * DPROJ + colz]);
    w2 = bf2f(zx16[(size_t)(b * 2048 + l0 - 1) * DPROJ + colz]);
  }
  bf16x8 rb[4];
#pragma unroll
  for (int li = 0; li < 32; li++) {
    int row = b * 2048 + l0 + li;
    float cur = bf2f(zx16[(size_t)row * DPROJ + colz]);
    float o = silu(cb + c0 * w0 + c1 * w1 + c2 * w2 + c3 * cur);
    xp16[(size_t)row * 1280 + j] = f2bf(o);
    float mult = isX ? dtp[(size_t)row * 16 + h] : 1.f;
    rb[li >> 3][li & 7] = (__bf16)(o * mult);
    w0 = w1; w1 = w2; w2 = cur;
  }
  unsigned short* base = nullptr;
  if (isX) {
    base = dtxt16 + ((size_t)(slot * 16 + h) * 64 + (j & 63)) * 2048 + l0;
  } else if (threadIdx.x < 128) {
    base = bt16 + ((size_t)slot * 128 + threadIdx.x) * 2048 + l0;
  }
  if (base) {
#pragma unroll
    for (int i = 0; i < 4; i++) *(bf16x8*)(base + i * 8) = rb[i];
  }
}

// ---------------- chunk states via MFMA: S[p=64][n-half=64] ----------------
__global__ __launch_bounds__(256) void states_mfma_k(
    float* __restrict__ scr0, long DS,
    const unsigned short* __restrict__ dtxt16, const unsigned short* __restrict__ bt16) {
  int h = blockIdx.x, c = blockIdx.y;
  int nh2 = blockIdx.z & 1, b = (blockIdx.z >> 1) & 1, dir = blockIdx.z >> 2;
  int slot = dir * 2 + b;
  float* scr = scr0 + (size_t)dir * DS;
  const float* Acs = scr + S_ACS;
  const float* Ttot = scr + S_TT;
  float* stout = scr + S_ST;
  int tid = threadIdx.x;
  int chidx = (b * NCH + c) * NH + h;
  size_t xtb = ((size_t)(slot * 16 + h) * 64) * 2048 + c * 256;
  size_t btb = ((size_t)slot * 128 + nh2 * 64) * 2048 + c * 256;
  __shared__ float sXs[256];
  __shared__ unsigned short At[64][40];
  __shared__ unsigned short Bt[64][40];
  {
    float a = Acs[(size_t)chidx * 256 + tid];
    float Tt = Ttot[chidx];
    sXs[tid] = __expf(Tt - a);
  }
  __syncthreads();
  int lane = tid & 63, w = tid >> 6;
  int fr = lane & 15, fq = lane >> 4;
  int sp = tid >> 2, sk = (tid & 3) * 8;
  f32x4 acc[4] = {};
  for (int k0 = 0; k0 < 256; k0 += 32) {
    {
      ushort4 xa = *(const ushort4*)&dtxt16[xtb + (size_t)sp * 2048 + k0 + sk];
      ushort4 xb = *(const ushort4*)&dtxt16[xtb + (size_t)sp * 2048 + k0 + sk + 4];
      float4 w0 = *(const float4*)&sXs[k0 + sk];
      float4 w1 = *(const float4*)&sXs[k0 + sk + 4];
      unsigned short tmp[8];
      tmp[0] = f2bf(bf2f(xa.x) * w0.x); tmp[1] = f2bf(bf2f(xa.y) * w0.y);
      tmp[2] = f2bf(bf2f(xa.z) * w0.z); tmp[3] = f2bf(bf2f(xa.w) * w0.w);
      tmp[4] = f2bf(bf2f(xb.x) * w1.x); tmp[5] = f2bf(bf2f(xb.y) * w1.y);
      tmp[6] = f2bf(bf2f(xb.z) * w1.z); tmp[7] = f2bf(bf2f(xb.w) * w1.w);
      *(ushort4*)&At[sp][sk]     = *(ushort4*)&tmp[0];
      *(ushort4*)&At[sp][sk + 4] = *(ushort4*)&tmp[4];
      *(bf16x8*)&Bt[sp][sk] = *(const bf16x8*)&bt16[btb + (size_t)sp * 2048 + k0 + sk];
    }
    __syncthreads();
    bf16x8 bb = *(const bf16x8*)&Bt[w * 16 + fr][fq * 8];
#pragma unroll
    for (int m = 0; m < 4; m++) {
      bf16x8 a = *(const bf16x8*)&At[m * 16 + fr][fq * 8];
      acc[m] = __builtin_amdgcn_mfma_f32_16x16x32_bf16(a, bb, acc[m], 0, 0, 0);
    }
    __syncthreads();
  }
#pragma unroll
  for (int m = 0; m < 4; m++) {
    int p = m * 16 + fq * 4;
    int nn = nh2 * 64 + w * 16 + fr;
#pragma unroll
    for (int j = 0; j < 4; j++)
      stout[(size_t)chidx * 8192 + (size_t)(p + j) * 128 + nn] = acc[m][j];
  }
}

// ---------------- inter-chunk recurrence (widened, Sin -> bf16) ----------------
__global__ __launch_bounds__(256) void recur_k(float* __restrict__ scr0, long DS) {
  int h = blockIdx.x;
  int b = blockIdx.y & 1, dir = blockIdx.y >> 1;
  float* scr = scr0 + (size_t)dir * DS;
  const float* st = scr + S_ST;
  const float* Ttot = scr + S_TT;
  unsigned short* Sin16 = (unsigned short*)(scr + S_SIN);
  int e0 = (blockIdx.z * 256 + threadIdx.x) * 4;   // 0..8188
  float4 s = make_float4(0.f, 0.f, 0.f, 0.f);
  for (int c = 0; c < 8; c++) {
    int chidx = (b * NCH + c) * NH + h;
    size_t base = (size_t)chidx * 8192 + e0;
    ushort4 o;
    o.x = f2bf(s.x); o.y = f2bf(s.y); o.z = f2bf(s.z); o.w = f2bf(s.w);
    *(ushort4*)&Sin16[base] = o;
    float dec = __expf(Ttot[chidx]);
    float4 v = *(const float4*)(st + base);
    s.x = s.x * dec + v.x; s.y = s.y * dec + v.y;
    s.z = s.z * dec + v.z; s.w = s.w * dec + v.w;
  }
}

// ---------------- fused Y_diag + Y_off, flash-style, bf16 out ----------------
__global__ __launch_bounds__(256) void ydo2_k(
    float* __restrict__ scr0, long DS, const unsigned short* __restrict__ dtxt16) {
  int h = blockIdx.x;
  int cy = blockIdx.y;
  int c = cy >> 2, lt = cy & 3;
  int b = blockIdx.z & 1, dir = blockIdx.z >> 1;
  int slot = dir * 2 + b;
  float* scr = scr0 + (size_t)dir * DS;
  const float* Acs = scr + S_ACS;
  const unsigned short* xp16 = (const unsigned short*)(scr + S_XP16);
  const unsigned short* Sin16 = (const unsigned short*)(scr + S_SIN);
  unsigned short* yhp16 = (unsigned short*)(scr + S_YHP16);
  int tid = threadIdx.x;
  int lane = tid & 63, w = tid >> 6;
  int fr = lane & 15, fq = lane >> 4;
  int row0 = b * 2048 + c * 256;
  int chidx = (b * NCH + c) * NH + h;
  int l0 = lt * 64;
  size_t xtb = ((size_t)(slot * 16 + h) * 64) * 2048 + c * 256;

  __shared__ unsigned short sBS[64][136];
  __shared__ unsigned short sXt[64][72];
  __shared__ unsigned short sP[64][72];
  __shared__ float sA[64], sAs[64];

  bf16x8 af[4];
#pragma unroll
  for (int k = 0; k < 4; k++)
    af[k] = *(const bf16x8*)&xp16[(size_t)(row0 + l0 + w * 16 + fr) * 1280 + 1152 + k * 32 + fq * 8];

#pragma unroll
  for (int i = 0; i < 4; i++) {
    int chunk = tid + i * 256;
    int p = chunk >> 4, n8 = (chunk & 15) * 8;
    *(bf16x8*)&sBS[p][n8] = *(const bf16x8*)&Sin16[(size_t)chidx * 8192 + p * 128 + n8];
  }
  if (tid < 64) sA[tid] = Acs[(size_t)chidx * 256 + l0 + tid];
  __syncthreads();

  f32x4 acc[4] = {};
#pragma unroll
  for (int n = 0; n < 4; n++) {
#pragma unroll
    for (int k = 0; k < 4; k++) {
      bf16x8 bb = *(const bf16x8*)&sBS[n * 16 + fr][k * 32 + fq * 8];
      acc[n] = __builtin_amdgcn_mfma_f32_16x16x32_bf16(af[k], bb, acc[n], 0, 0, 0);
    }
  }
  {
    int lrow = w * 16 + fq * 4;
    float el[4];
#pragma unroll
    for (int j = 0; j < 4; j++) el[j] = __expf(sA[lrow + j]);
#pragma unroll
    for (int n = 0; n < 4; n++)
#pragma unroll
      for (int j = 0; j < 4; j++) acc[n][j] *= el[j];
  }

  for (int st = 0; st <= lt; st++) {
    __syncthreads();
    int srow0 = row0 + st * 64;
#pragma unroll
    for (int i = 0; i < 4; i++) {
      int chunk = tid + i * 256;
      int r = chunk >> 4, c8 = (chunk & 15) * 8;
      *(bf16x8*)&sBS[r][c8] = *(const bf16x8*)&xp16[(size_t)(srow0 + r) * 1280 + 1024 + c8];
    }
#pragma unroll
    for (int i = 0; i < 2; i++) {
      int chunk = tid + i * 256;
      int p = chunk >> 3, s8 = (chunk & 7) * 8;
      *(bf16x8*)&sXt[p][s8] = *(const bf16x8*)&dtxt16[xtb + (size_t)p * 2048 + st * 64 + s8];
    }
    if (tid < 64) sAs[tid] = Acs[(size_t)chidx * 256 + st * 64 + tid];
    __syncthreads();

    f32x4 cb[4] = {};
#pragma unroll
    for (int n = 0; n < 4; n++) {
#pragma unroll
      for (int k = 0; k < 4; k++) {
        bf16x8 bb = *(const bf16x8*)&sBS[n * 16 + fr][k * 32 + fq * 8];
        cb[n] = __builtin_amdgcn_mfma_f32_16x16x32_bf16(af[k], bb, cb[n], 0, 0, 0);
      }
    }
    {
      int lrow = w * 16 + fq * 4;
      float al[4];
#pragma unroll
      for (int j = 0; j < 4; j++) al[j] = sA[lrow + j];
      bool full = (st < lt);
#pragma unroll
      for (int n = 0; n < 4; n++) {
        int srow = n * 16 + fr;
        float as_ = sAs[srow];
#pragma unroll
        for (int j = 0; j < 4; j++) {
          float v = (full || srow <= lrow + j) ? cb[n][j] * __expf(al[j] - as_) : 0.f;
          sP[lrow + j][srow] = f2bf(v);
        }
      }
    }
#pragma unroll
    for (int k2 = 0; k2 < 2; k2++) {
      bf16x8 pa = *(const bf16x8*)&sP[w * 16 + fr][k2 * 32 + fq * 8];
#pragma unroll
      for (int n = 0; n < 4; n++) {
        bf16x8 bb = *(const bf16x8*)&sXt[n * 16 + fr][k2 * 32 + fq * 8];
        acc[n] = __builtin_amdgcn_mfma_f32_16x16x32_bf16(pa, bb, acc[n], 0, 0, 0);
      }
    }
  }

#pragma unroll
  for (int n = 0; n < 4; n++) {
    int p = n * 16 + fr;
#pragma unroll
    for (int j = 0; j < 4; j++) {
      int row = row0 + l0 + w * 16 + fq * 4 + j;
      yhp16[(size_t)row * 1024 + h * 64 + p] = f2bf(acc[n][j]);
    }
  }
}

// ---------------- gate + x*D + RMS norm, all bf16, in place ----------------
__global__ __launch_bounds__(256) void gate_rms_k(
    float* __restrict__ scr0, long DS,
    const float* __restrict__ fD, const float* __restrict__ bD,
    const float* __restrict__ fnw, const float* __restrict__ bnw) {
  int row = blockIdx.x;
  int dir = blockIdx.y;
  float* scr = scr0 + (size_t)dir * DS;
  unsigned short* yhp16 = (unsigned short*)(scr + S_YHP16);
  const unsigned short* xp16 = (const unsigned short*)(scr + S_XP16);
  const unsigned short* zx16 = (const unsigned short*)(scr + S_ZX16);
  const float* Dv = dir ? bD : fD;
  const float* nw = dir ? bnw : fnw;
  float g[4];
  float ss = 0.f;
#pragma unroll
  for (int k = 0; k < 4; k++) {
    int i = threadIdx.x + k * 256;
    int h = i >> 6;
    float y = bf2f(yhp16[(size_t)row * 1024 + i]) +
              bf2f(xp16[(size_t)row * 1280 + i]) * Dv[h];
    float z = bf2f(zx16[(size_t)row * DPROJ + i]);
    float gg = y * silu(z);
    ss += gg * gg;
    g[k] = gg;
  }
  for (int o = 32; o > 0; o >>= 1) ss += __shfl_down(ss, o);
  __shared__ float red[5];
  int wid = threadIdx.x >> 6;
  if ((threadIdx.x & 63) == 0) red[wid] = ss;
  __syncthreads();
  if (threadIdx.x == 0) red[4] = red[0] + red[1] + red[2] + red[3];
  __syncthreads();
  float rstd = rsqrtf(red[4] / 1024.f + 1e-5f);
#pragma unroll
  for (int k = 0; k < 4; k++) {
    int i = threadIdx.x + k * 256;
    yhp16[(size_t)row * 1024 + i] = f2bf(g[k] * rstd * nw[i]);
  }
}

// ---------------- fused output mega-GEMM, split-K=3 ----------------
__global__ __launch_bounds__(256) void gemm_f2_k(
    const unsigned short* __restrict__ yhpf16, const unsigned short* __restrict__ yhpb16,
    const unsigned short* __restrict__ t16, const unsigned short* __restrict__ W16,
    float* __restrict__ prp) {
  int n0 = blockIdx.x * 64, m0 = blockIdx.y * 64, kpart = blockIdx.z;
  int kbase = kpart * 768;
  __shared__ unsigned short As[2048];
  __shared__ unsigned short Bs[2048];
  int tid = threadIdx.x;
  int lane = tid & 63, wid = tid >> 6;
  int wr = (wid >> 1) * 32, wc = (wid & 1) * 32;
  int fr = lane & 15, fq = lane >> 4;
  int r = tid >> 2, c8 = (tid & 3) * 8;
  f32x4 acc[2][2] = {};
  for (int ki = 0; ki < 24; ki++) {
    int k0 = kbase + ki * 32;
    int gk = k0 + c8;
    {
      const unsigned short* asrc;
      const unsigned short* bsrc;
      int gm = m0 + r;
      int o = n0 + r;
      if (gk < 1024) {
        asrc = yhpf16 + (size_t)gm * 1024 + gk;
        bsrc = W16 + (size_t)o * 1024 + gk;
      } else if (gk < 2048) {
        asrc = yhpb16 + (size_t)(gm ^ 2047) * 1024 + (gk - 1024);
        bsrc = W16 + 262144 + (size_t)o * 1024 + (gk - 1024);
      } else {
        asrc = t16 + (size_t)gm * 256 + (gk - 2048);
        bsrc = W16 + 524288 + (size_t)o * 256 + (gk - 2048);
      }
      int ldsoff = wid * 512;
      gl_lds16(asrc, As + ldsoff);
      gl_lds16(bsrc, Bs + ldsoff);
    }
    __syncthreads();
    bf16x8 a[2], b[2];
#pragma unroll
    for (int m = 0; m < 2; m++) a[m] = *(const bf16x8*)&As[(wr + m * 16 + fr) * 32 + fq * 8];
#pragma unroll
    for (int n = 0; n < 2; n++) b[n] = *(const bf16x8*)&Bs[(wc + n * 16 + fr) * 32 + fq * 8];
#pragma unroll
    for (int m = 0; m < 2; m++)
#pragma unroll
      for (int n = 0; n < 2; n++)
        acc[m][n] = __builtin_amdgcn_mfma_f32_16x16x32_bf16(a[m], b[n], acc[m][n], 0, 0, 0);
    __syncthreads();
  }
  float* C = prp + (size_t)kpart * 1048576;
#pragma unroll
  for (int m = 0; m < 2; m++) {
    int row = m0 + wr + m * 16 + fq * 4;
#pragma unroll
    for (int n = 0; n < 2; n++) {
      int col = n0 + wc + n * 16 + fr;
#pragma unroll
      for (int j = 0; j < 4; j++) C[(size_t)(row + j) * 256 + col] = acc[m][n][j];
    }
  }
}

// ---------------- out = x + (pr0+pr1+pr2)^T + proj_b ----------------
__global__ __launch_bounds__(256) void final_add3_k(const float* __restrict__ x,
                                                    const float* __restrict__ prp,
                                                    const float* __restrict__ pb,
                                                    float* __restrict__ out) {
  int l0 = blockIdx.x * 32, c0 = blockIdx.y * 32, b = blockIdx.z;
  int tx = threadIdx.x & 31, ty = threadIdx.x >> 5;
  __shared__ float tile[32][33];
#pragma unroll
  for (int i = 0; i < 4; i++) {
    int ll = ty + i * 8;
    size_t idx = (size_t)(b * 2048 + l0 + ll) * 256 + c0 + tx;
    tile[ll][tx] = prp[idx] + prp[idx + 1048576] + prp[idx + 2097152];
  }
  __syncthreads();
#pragma unroll
  for (int i = 0; i < 4; i++) {
    int ch = c0 + ty + i * 8;
    size_t o = (size_t)b * 524288 + (size_t)ch * 2048 + l0 + tx;
    out[o] = x[o] + tile[tx][ty + i * 8] + pb[ch];
  }
}

}  // namespace

extern "C" void kernel_launch(void* const* d_in, const int* in_sizes, int n_in,
                              void* d_out, int out_size, void* d_ws, size_t ws_size,
                              hipStream_t stream) {
  (void)in_sizes; (void)n_in; (void)out_size; (void)ws_size;
  const float* x      = (const float*)d_in[0];
  const float* gn_w   = (const float*)d_in[1];
  const float* gn_b   = (const float*)d_in[2];
  const float* proj_w = (const float*)d_in[3];
  const float* proj_b = (const float*)d_in[4];
  const float* fiw  = (const float*)d_in[5];
  const float* fcw  = (const float*)d_in[6];
  const float* fcb  = (const float*)d_in[7];
  const float* fdtb = (const float*)d_in[8];
  const float* fAl  = (const float*)d_in[9];
  const float* fD   = (const float*)d_in[10];
  const float* fnw  = (const float*)d_in[11];
  const float* fow  = (const float*)d_in[12];
  const float* biw  = (const float*)d_in[13];
  const float* bcw  = (const float*)d_in[14];
  const float* bcb  = (const float*)d_in[15];
  const float* bdtb = (const float*)d_in[16];
  const float* bAl  = (const float*)d_in[17];
  const float* bD   = (const float*)d_in[18];
  const float* bnw  = (const float*)d_in[19];
  const float* bow  = (const float*)d_in[20];
  float* out = (float*)d_out;
  float* ws  = (float*)d_ws;
  float* scr0 = ws + F_SCR0;
  const long DS = (long)SZ_SCR;

  unsigned short* t16     = (unsigned short*)(ws + F_BF);
  unsigned short* inw16   = t16 + 1048576;
  unsigned short* W16     = inw16 + 1187840;   // Wf(262144) | Wb(262144) | tw(65536)
  unsigned short* dtxt16  = W16 + 655360;
  unsigned short* bt16    = dtxt16 + 8388608;
  unsigned short* zx16    = (unsigned short*)(scr0 + S_ZX16);
  unsigned short* yhpf16  = (unsigned short*)(scr0 + S_YHP16);
  unsigned short* yhpb16  = (unsigned short*)(scr0 + DS + S_YHP16);
  float* prp = ws + F_PRP;

  // merged prep: stats_partial | weight converts | wprep
  prep_k<<<2124, 256, 0, stream>>>(x, ws + F_PART, fiw, biw, proj_w, fow, bow, inw16, W16);
  // normalize + transpose (inline stats-final)
  normt2_k<<<dim3(64, 8, 2), 256, 0, stream>>>(x, gn_w, gn_b, ws + F_PART, ws + F_T, t16);
  // co-launch: in_proj GEMM (1216 blocks) | dt+scan (512 blocks)
  inproj_dscan_k<<<1728, 256, 0, stream>>>(
      t16, ws + F_T, inw16, fiw, biw, fdtb, bdtb, fAl, bAl, scr0, DS, zx16);
  // conv + silu + fused dtX^T / B^T transpose (32-l chunks)
  convt_k<<<dim3(5, 64, 4), 256, 0, stream>>>(fcw, bcw, fcb, bcb, scr0, DS, dtxt16, bt16);
  // chunk states
  states_mfma_k<<<dim3(NH, NCH, 8), 256, 0, stream>>>(scr0, DS, dtxt16, bt16);
  // inter-chunk recurrence (widened, Sin -> bf16)
  recur_k<<<dim3(NH, 4, 8), 256, 0, stream>>>(scr0, DS);
  // fused Y_diag + Y_off
  ydo2_k<<<dim3(NH, NCH * 4, 4), 256, 0, stream>>>(scr0, DS, dtxt16);
  // gate + RMS norm (in place on yhp16)
  gate_rms_k<<<dim3(4096, 2), 256, 0, stream>>>(scr0, DS, fD, bD, fnw, bnw);
  // fused output mega-GEMM, split-K=3
  gemm_f2_k<<<dim3(4, 64, 3), 256, 0, stream>>>(yhpf16, yhpb16, t16, W16, prp);
  // out = x + sum(pr)^T + proj_b
  final_add3_k<<<dim3(64, 8, 2), 256, 0, stream>>>(x, prp, proj_b, out);
}